// Round 2
// baseline (8443.995 us; speedup 1.0000x reference)
//
#include <hip/hip_runtime.h>
#include <hip/hip_bf16.h>
#include <math.h>

#define DIN 128
#define DH 256
#define DOUT 128
#define NLAYERS 8
#define EPSLN 1e-5f

typedef __hip_bfloat16 bf16;

__device__ __forceinline__ float ldf(const void* p, size_t idx, int isbf) {
    if (isbf) return __bfloat162float(((const bf16*)p)[idx]);
    return ((const float*)p)[idx];
}

// ---------------- dtype probe: low-16-bit exponent-field vote ----------------
__global__ void k_detect(const unsigned int* __restrict__ xw, int* __restrict__ flag) {
    __shared__ int cnt;
    if (threadIdx.x == 0) cnt = 0;
    __syncthreads();
    unsigned int w = xw[threadIdx.x];
    int e = (w >> 7) & 0xFF;          // exponent of the LOW bf16 if packed-bf16
    if (e >= 112 && e <= 140) atomicAdd(&cnt, 1);
    __syncthreads();
    if (threadIdx.x == 0) *flag = (cnt >= 128) ? 1 : 0;
}

// ---------------- degree / normalization ----------------
__global__ void k_init_deg(float* __restrict__ dis, int N) {
    int i = blockIdx.x * blockDim.x + threadIdx.x;
    if (i < N) dis[i] = 1.0f;  // self-loop contributes 1
}

__global__ void k_deg_scatter(const int* __restrict__ col, float* __restrict__ dis, int E) {
    int e = blockIdx.x * blockDim.x + threadIdx.x;
    if (e < E) atomicAdd(&dis[col[e]], 1.0f);
}

__global__ void k_deg_rsqrt(float* __restrict__ dis, int N) {
    int i = blockIdx.x * blockDim.x + threadIdx.x;
    if (i < N) dis[i] = rsqrtf(dis[i]);
}

__global__ void k_zero_stats(float* __restrict__ stats) {
    int t = threadIdx.x;
    if (t < 8) stats[t] = 0.0f;
}

// ---------------- GEMM 1: x0 = relu(x @ lin1_w + b); also h=x0, agg=d^2*x0 ----------------
__global__ __launch_bounds__(256) void gemm_lin1(
    const void* __restrict__ A, const void* __restrict__ B,
    const void* __restrict__ bias, const float* __restrict__ dis,
    const int* __restrict__ flag,
    bf16* __restrict__ x0, bf16* __restrict__ h, float* __restrict__ agg, int Nn)
{
    const int BM = 64, BN = 64, BK = 16, AS = 17;
    __shared__ float As[BM * AS], Bs[BK * BN];
    const int isbf = *flag;
    int t = threadIdx.x;
    int tx = t & 15, ty = t >> 4;
    int row0 = blockIdx.x * BM, col0 = blockIdx.y * BN;
    float acc[4][4] = {};
    for (int k0 = 0; k0 < DIN; k0 += BK) {
        #pragma unroll
        for (int i = 0; i < 4; i++) {
            int idx = t * 4 + i;
            int r = idx >> 4, c = idx & 15;
            int gr = row0 + r;
            As[r * AS + c] = (gr < Nn) ? ldf(A, (size_t)gr * DIN + k0 + c, isbf) : 0.f;
        }
        #pragma unroll
        for (int i = 0; i < 4; i++) {
            int idx = t * 4 + i;
            int r = idx >> 6, c = idx & 63;
            Bs[r * BN + c] = ldf(B, (size_t)(k0 + r) * DH + col0 + c, isbf);
        }
        __syncthreads();
        #pragma unroll
        for (int kk = 0; kk < BK; kk++) {
            float a[4], b[4];
            #pragma unroll
            for (int i = 0; i < 4; i++) a[i] = As[(ty * 4 + i) * AS + kk];
            #pragma unroll
            for (int j = 0; j < 4; j++) b[j] = Bs[kk * BN + tx * 4 + j];
            #pragma unroll
            for (int i = 0; i < 4; i++)
                #pragma unroll
                for (int j = 0; j < 4; j++) acc[i][j] = fmaf(a[i], b[j], acc[i][j]);
        }
        __syncthreads();
    }
    #pragma unroll
    for (int i = 0; i < 4; i++) {
        int gr = row0 + ty * 4 + i;
        if (gr >= Nn) continue;
        float d = dis[gr]; float d2 = d * d;
        #pragma unroll
        for (int j = 0; j < 4; j++) {
            int gc = col0 + tx * 4 + j;
            float v = acc[i][j] + ldf(bias, gc, isbf);
            v = v > 0.f ? v : 0.f;
            bf16 vb = __float2bfloat16(v);
            size_t off = (size_t)gr * DH + gc;
            x0[off] = vb;
            h[off] = vb;
            agg[off] = d2 * v;  // self-loop seed for layer-0 scatter
        }
    }
}

// ---------------- edge scatter: agg[col] += dis[row]*dis[col]*h[row] ----------------
#define EPB 16
__global__ __launch_bounds__(256) void k_edge_scatter(
    const int* __restrict__ rows, const int* __restrict__ cols,
    const float* __restrict__ dis, const bf16* __restrict__ h,
    float* __restrict__ agg, int E)
{
    int t = threadIdx.x;
    int e0 = blockIdx.x * EPB;
    for (int j = 0; j < EPB; j++) {
        int e = e0 + j;
        if (e >= E) break;
        int r = rows[e], c = cols[e];
        float w = dis[r] * dis[c];
        float hv = __bfloat162float(h[(size_t)r * DH + t]);
        atomicAdd(&agg[(size_t)c * DH + t], w * hv);
    }
}

// ---------------- layer GEMM: h = c0*(agg+x0) + c1*(agg@W1 + x0@W2), fused LN sums ----------------
__global__ __launch_bounds__(256) void gemm_layer(
    const float* __restrict__ agg, const bf16* __restrict__ x0,
    const void* __restrict__ W1, const void* __restrict__ W2, size_t woff,
    const int* __restrict__ flag,
    bf16* __restrict__ h, float* __restrict__ stats, float c0, float c1, int Nn)
{
    const int BM = 64, BN = 64, BK = 16, AS = 17;
    __shared__ float As[BM * AS], Bs[BK * BN];
    const int isbf = *flag;
    int t = threadIdx.x;
    int tx = t & 15, ty = t >> 4;
    int row0 = blockIdx.x * BM, col0 = blockIdx.y * BN;
    float acc[4][4] = {};
    for (int k0 = 0; k0 < 2 * DH; k0 += BK) {
        const void* Bsrc = (k0 < DH) ? W1 : W2;
        int kb = (k0 < DH) ? k0 : k0 - DH;
        int useAgg = (k0 < DH) ? 1 : 0;
        #pragma unroll
        for (int i = 0; i < 4; i++) {
            int idx = t * 4 + i;
            int r = idx >> 4, c = idx & 15;
            int gr = row0 + r;
            float av = 0.f;
            if (gr < Nn) {
                size_t off = (size_t)gr * DH + kb + c;
                av = useAgg ? agg[off] : __bfloat162float(x0[off]);
            }
            As[r * AS + c] = av;
        }
        #pragma unroll
        for (int i = 0; i < 4; i++) {
            int idx = t * 4 + i;
            int r = idx >> 6, c = idx & 63;
            Bs[r * BN + c] = ldf(Bsrc, woff + (size_t)(kb + r) * DH + col0 + c, isbf);
        }
        __syncthreads();
        #pragma unroll
        for (int kk = 0; kk < BK; kk++) {
            float a[4], b[4];
            #pragma unroll
            for (int i = 0; i < 4; i++) a[i] = As[(ty * 4 + i) * AS + kk];
            #pragma unroll
            for (int j = 0; j < 4; j++) b[j] = Bs[kk * BN + tx * 4 + j];
            #pragma unroll
            for (int i = 0; i < 4; i++)
                #pragma unroll
                for (int j = 0; j < 4; j++) acc[i][j] = fmaf(a[i], b[j], acc[i][j]);
        }
        __syncthreads();
    }
    float lsum = 0.f, lsq = 0.f;
    #pragma unroll
    for (int i = 0; i < 4; i++) {
        int gr = row0 + ty * 4 + i;
        if (gr >= Nn) continue;
        #pragma unroll
        for (int j = 0; j < 4; j++) {
            int gc = col0 + tx * 4 + j;
            size_t off = (size_t)gr * DH + gc;
            float e = agg[off] + __bfloat162float(x0[off]);
            float v = c0 * e + c1 * acc[i][j];
            h[off] = __float2bfloat16(v);
            lsum += v;
            lsq += v * v;
        }
    }
    __syncthreads();
    As[t] = lsum; Bs[t] = lsq;
    __syncthreads();
    for (int s = 128; s > 0; s >>= 1) {
        if (t < s) { As[t] += As[t + s]; Bs[t] += Bs[t + s]; }
        __syncthreads();
    }
    if (t == 0) {
        atomicAdd(&stats[0], As[0]);
        atomicAdd(&stats[1], Bs[0]);
    }
}

__global__ void k_finalize(float* __restrict__ stats, float invTotal) {
    float mu = stats[0] * invTotal;
    float var = stats[1] * invTotal - mu * mu;
    var = var > 0.f ? var : 0.f;
    stats[2] = mu;
    stats[3] = 1.0f / (sqrtf(var) + EPSLN);
    stats[0] = 0.f;
    stats[1] = 0.f;
}

// ---------------- layernorm apply + relu; seed next agg with self-loop ----------------
__global__ __launch_bounds__(256) void k_apply(
    bf16* __restrict__ h, float* __restrict__ agg,
    const float* __restrict__ dis, const float* __restrict__ stats,
    const void* __restrict__ g, const void* __restrict__ b, size_t loff,
    const int* __restrict__ flag, int total)
{
    int idx = blockIdx.x * 256 + threadIdx.x;
    if (idx >= total) return;
    const int isbf = *flag;
    float mu = stats[2], inv = stats[3];
    int j = idx & (DH - 1);
    int n = idx >> 8;
    float v = (__bfloat162float(h[idx]) - mu) * inv;
    v = fmaf(ldf(g, loff + j, isbf), v, ldf(b, loff + j, isbf));
    v = v > 0.f ? v : 0.f;
    h[idx] = __float2bfloat16(v);
    float d = dis[n];
    agg[idx] = d * d * v;
}

// ---------------- GEMM 2: out = relu(h @ lin2_w + b2) ----------------
__global__ __launch_bounds__(256) void gemm_lin2(
    const bf16* __restrict__ A, const void* __restrict__ B,
    const void* __restrict__ bias, const int* __restrict__ flag,
    void* __restrict__ out, int Nn)
{
    const int BM = 64, BN = 64, BK = 16, AS = 17;
    __shared__ float As[BM * AS], Bs[BK * BN];
    const int isbf = *flag;
    int t = threadIdx.x;
    int tx = t & 15, ty = t >> 4;
    int row0 = blockIdx.x * BM, col0 = blockIdx.y * BN;
    float acc[4][4] = {};
    for (int k0 = 0; k0 < DH; k0 += BK) {
        #pragma unroll
        for (int i = 0; i < 4; i++) {
            int idx = t * 4 + i;
            int r = idx >> 4, c = idx & 15;
            int gr = row0 + r;
            As[r * AS + c] = (gr < Nn) ? __bfloat162float(A[(size_t)gr * DH + k0 + c]) : 0.f;
        }
        #pragma unroll
        for (int i = 0; i < 4; i++) {
            int idx = t * 4 + i;
            int r = idx >> 6, c = idx & 63;
            Bs[r * BN + c] = ldf(B, (size_t)(k0 + r) * DOUT + col0 + c, isbf);
        }
        __syncthreads();
        #pragma unroll
        for (int kk = 0; kk < BK; kk++) {
            float a[4], b[4];
            #pragma unroll
            for (int i = 0; i < 4; i++) a[i] = As[(ty * 4 + i) * AS + kk];
            #pragma unroll
            for (int j = 0; j < 4; j++) b[j] = Bs[kk * BN + tx * 4 + j];
            #pragma unroll
            for (int i = 0; i < 4; i++)
                #pragma unroll
                for (int j = 0; j < 4; j++) acc[i][j] = fmaf(a[i], b[j], acc[i][j]);
        }
        __syncthreads();
    }
    #pragma unroll
    for (int i = 0; i < 4; i++) {
        int gr = row0 + ty * 4 + i;
        if (gr >= Nn) continue;
        #pragma unroll
        for (int j = 0; j < 4; j++) {
            int gc = col0 + tx * 4 + j;
            float v = acc[i][j] + ldf(bias, gc, isbf);
            v = v > 0.f ? v : 0.f;
            size_t off = (size_t)gr * DOUT + gc;
            if (isbf) ((bf16*)out)[off] = __float2bfloat16(v);
            else      ((float*)out)[off] = v;
        }
    }
}

extern "C" void kernel_launch(void* const* d_in, const int* in_sizes, int n_in,
                              void* d_out, int out_size, void* d_ws, size_t ws_size,
                              hipStream_t stream) {
    const void* x      = d_in[0];
    const int*  ei     = (const int*)d_in[1];
    const void* lin1_w = d_in[2];
    const void* lin1_b = d_in[3];
    const void* conv_w1= d_in[4];
    const void* conv_w2= d_in[5];
    const void* gam    = d_in[6];
    const void* bet    = d_in[7];
    const void* lin2_w = d_in[8];
    const void* lin2_b = d_in[9];

    const int N = in_sizes[0] / DIN;
    const int E = in_sizes[1] / 2;
    const int* rows = ei;
    const int* cols = ei + E;

    float* ws = (float*)d_ws;
    size_t Nr = ((size_t)N + 255) / 256 * 256;
    const size_t NDH = (size_t)N * DH;
    float* dis   = ws;
    float* stats = ws + Nr;
    int*   flag  = (int*)(ws + Nr + 8);
    float* agg   = ws + Nr + 64;
    bf16*  x0    = (bf16*)(agg + NDH);
    bf16*  h     = x0 + NDH;

    dim3 blk(256);
    dim3 gN((N + 255) / 256);
    dim3 gE((E + 255) / 256);
    dim3 gMM((N + 63) / 64, DH / 64);
    dim3 gMM2((N + 63) / 64, DOUT / 64);
    dim3 gScat((E + EPB - 1) / EPB);
    dim3 gElem((unsigned)((NDH + 255) / 256));

    k_detect<<<1, 256, 0, stream>>>((const unsigned int*)x, flag);
    k_init_deg<<<gN, blk, 0, stream>>>(dis, N);
    k_deg_scatter<<<gE, blk, 0, stream>>>(cols, dis, E);
    k_deg_rsqrt<<<gN, blk, 0, stream>>>(dis, N);
    k_zero_stats<<<1, 64, 0, stream>>>(stats);

    gemm_lin1<<<gMM, blk, 0, stream>>>(x, lin1_w, lin1_b, dis, flag, x0, h, agg, N);

    const float invTotal = 1.0f / ((float)N * (float)DH);
    for (int l = 0; l < NLAYERS; l++) {
        float bl = logf(1.0f / (float)(l + 1) + 1.0f);
        float c0 = 0.5f * (1.0f - bl);
        float c1 = 0.5f * bl;
        k_edge_scatter<<<gScat, blk, 0, stream>>>(rows, cols, dis, h, agg, E);
        gemm_layer<<<gMM, blk, 0, stream>>>(agg, x0, conv_w1, conv_w2,
                                            (size_t)l * DH * DH, flag,
                                            h, stats, c0, c1, N);
        k_finalize<<<1, 1, 0, stream>>>(stats, invTotal);
        k_apply<<<gElem, blk, 0, stream>>>(h, agg, dis, stats, gam, bet,
                                           (size_t)l * DH, flag, (int)NDH);
    }
    gemm_lin2<<<gMM2, blk, 0, stream>>>(h, lin2_w, lin2_b, flag, d_out, N);
}

// Round 4
// 2210.655 us; speedup vs baseline: 3.8197x; 3.8197x over previous
//
#include <hip/hip_runtime.h>
#include <hip/hip_bf16.h>
#include <math.h>

#define DIN 128
#define DH 256
#define DOUT 128
#define NLAYERS 8
#define EPSLN 1e-5f

typedef __hip_bfloat16 bf16;
typedef __attribute__((ext_vector_type(8))) short short8;
typedef __attribute__((ext_vector_type(4))) float f32x4;

__device__ __forceinline__ float ldf(const void* p, size_t idx, int isbf) {
    if (isbf) return __bfloat162float(((const bf16*)p)[idx]);
    return ((const float*)p)[idx];
}
__device__ __forceinline__ short f2s(float v) {
    bf16 b = __float2bfloat16(v);
    return *reinterpret_cast<short*>(&b);
}

// ---------------- dtype probe ----------------
__global__ void k_detect(const unsigned int* __restrict__ xw, int* __restrict__ flag) {
    __shared__ int cnt;
    if (threadIdx.x == 0) cnt = 0;
    __syncthreads();
    unsigned int w = xw[threadIdx.x];
    int e = (w >> 7) & 0xFF;
    if (e >= 112 && e <= 140) atomicAdd(&cnt, 1);
    __syncthreads();
    if (threadIdx.x == 0) *flag = (cnt >= 128) ? 1 : 0;
}

// ---------------- degree + CSR build ----------------
__global__ void k_init_cnt(int* __restrict__ cnt, int N) {
    int i = blockIdx.x * blockDim.x + threadIdx.x;
    if (i < N) cnt[i] = 0;
}
__global__ void k_count(const int* __restrict__ cols, int* __restrict__ cnt, int E) {
    int e = blockIdx.x * blockDim.x + threadIdx.x;
    if (e < E) atomicAdd(&cnt[cols[e]], 1);
}
__global__ void k_dis(const int* __restrict__ cnt, float* __restrict__ dis, int N) {
    int i = blockIdx.x * blockDim.x + threadIdx.x;
    if (i < N) dis[i] = rsqrtf(1.0f + (float)cnt[i]);
}
__global__ void k_scan1(const int* __restrict__ cnt, int* __restrict__ rowptr,
                        int* __restrict__ bsum, int N) {
    __shared__ int s[256];
    int t = threadIdx.x;
    int i = blockIdx.x * 256 + t;
    s[t] = (i < N) ? cnt[i] : 0;
    __syncthreads();
    for (int off = 1; off < 256; off <<= 1) {
        int x = (t >= off) ? s[t - off] : 0;
        __syncthreads();
        s[t] += x;
        __syncthreads();
    }
    if (i < N) rowptr[i + 1] = s[t];
    if (t == 255) bsum[blockIdx.x] = s[255];
}
__global__ void k_scan2(int* __restrict__ bsum, int nb) {
    __shared__ int s[256];
    int t = threadIdx.x;
    s[t] = (t < nb) ? bsum[t] : 0;
    __syncthreads();
    for (int off = 1; off < 256; off <<= 1) {
        int x = (t >= off) ? s[t - off] : 0;
        __syncthreads();
        s[t] += x;
        __syncthreads();
    }
    if (t < nb) bsum[t] = s[t];
}
__global__ void k_scan3(int* __restrict__ rowptr, const int* __restrict__ bsum, int N) {
    int i = blockIdx.x * 256 + threadIdx.x;
    if (i == 0) rowptr[0] = 0;
    if (i < N && blockIdx.x > 0) rowptr[i + 1] += bsum[blockIdx.x - 1];
}
__global__ void k_cursor(const int* __restrict__ rowptr, int* __restrict__ cursor, int N) {
    int i = blockIdx.x * 256 + threadIdx.x;
    if (i < N) cursor[i] = rowptr[i];
}
__global__ void k_fill(const int* __restrict__ rows, const int* __restrict__ cols,
                       int* __restrict__ cursor, int* __restrict__ csr, int E) {
    int e = blockIdx.x * blockDim.x + threadIdx.x;
    if (e < E) {
        int c = cols[e], r = rows[e];
        int pos = atomicAdd(&cursor[c], 1);
        csr[pos] = r;
    }
}

__global__ void k_zero_stats(float* __restrict__ stats) {
    int t = threadIdx.x;
    if (t < 8) stats[t] = 0.0f;
}

// ---------------- weight transpose+convert: wt[z][n][k] = W_z[k][n] (bf16) ----------------
__global__ void k_transw(const void* __restrict__ w1, const void* __restrict__ w2,
                         const int* __restrict__ flag, short* __restrict__ wt) {
    __shared__ float tile[32][33];
    int z = blockIdx.z;
    int lay = z >> 1, m = z & 1;
    const void* src = m ? w2 : w1;
    size_t sbase = (size_t)lay * 65536;
    short* dst = wt + (size_t)lay * 131072 + (size_t)m * 65536;
    int isbf = *flag;
    int tx = threadIdx.x, ty = threadIdx.y;     // (32,8)
    int n0 = blockIdx.x * 32, k0 = blockIdx.y * 32;
    #pragma unroll
    for (int i = 0; i < 4; i++) {
        int k = k0 + ty + i * 8;
        tile[ty + i * 8][tx] = ldf(src, sbase + (size_t)k * 256 + n0 + tx, isbf);
    }
    __syncthreads();
    #pragma unroll
    for (int i = 0; i < 4; i++) {
        int n = n0 + ty + i * 8;
        dst[(size_t)n * 256 + k0 + tx] = f2s(tile[tx][ty + i * 8]);
    }
}

// ---------------- GEMM 1 (SIMT): x0 = relu(x @ lin1_w + b); h = x0 ----------------
__global__ __launch_bounds__(256) void gemm_lin1(
    const void* __restrict__ A, const void* __restrict__ B,
    const void* __restrict__ bias, const int* __restrict__ flag,
    bf16* __restrict__ x0, bf16* __restrict__ h, int Nn)
{
    const int BM = 64, BN = 64, BK = 16, AS = 17;
    __shared__ float As[BM * AS], Bs[BK * BN];
    const int isbf = *flag;
    int t = threadIdx.x;
    int tx = t & 15, ty = t >> 4;
    int row0 = blockIdx.x * BM, col0 = blockIdx.y * BN;
    float acc[4][4] = {};
    for (int k0 = 0; k0 < DIN; k0 += BK) {
        #pragma unroll
        for (int i = 0; i < 4; i++) {
            int idx = t * 4 + i;
            int r = idx >> 4, c = idx & 15;
            int gr = row0 + r;
            As[r * AS + c] = (gr < Nn) ? ldf(A, (size_t)gr * DIN + k0 + c, isbf) : 0.f;
        }
        #pragma unroll
        for (int i = 0; i < 4; i++) {
            int idx = t * 4 + i;
            int r = idx >> 6, c = idx & 63;
            Bs[r * BN + c] = ldf(B, (size_t)(k0 + r) * DH + col0 + c, isbf);
        }
        __syncthreads();
        #pragma unroll
        for (int kk = 0; kk < BK; kk++) {
            float a[4], b[4];
            #pragma unroll
            for (int i = 0; i < 4; i++) a[i] = As[(ty * 4 + i) * AS + kk];
            #pragma unroll
            for (int j = 0; j < 4; j++) b[j] = Bs[kk * BN + tx * 4 + j];
            #pragma unroll
            for (int i = 0; i < 4; i++)
                #pragma unroll
                for (int j = 0; j < 4; j++) acc[i][j] = fmaf(a[i], b[j], acc[i][j]);
        }
        __syncthreads();
    }
    #pragma unroll
    for (int i = 0; i < 4; i++) {
        int gr = row0 + ty * 4 + i;
        if (gr >= Nn) continue;
        #pragma unroll
        for (int j = 0; j < 4; j++) {
            int gc = col0 + tx * 4 + j;
            float v = acc[i][j] + ldf(bias, gc, isbf);
            v = v > 0.f ? v : 0.f;
            bf16 vb = __float2bfloat16(v);
            size_t off = (size_t)gr * DH + gc;
            x0[off] = vb;
            h[off] = vb;
        }
    }
}

// ---------------- CSR gather: agg[c] = dc*(dc*h[c] + sum_r dis[r]*h[r]) ----------------
__global__ __launch_bounds__(256) void k_gather(
    const int* __restrict__ rowptr, const int* __restrict__ csr,
    const float* __restrict__ dis, const bf16* __restrict__ h,
    bf16* __restrict__ agg)
{
    int c = blockIdx.x;
    int t = threadIdx.x;
    float dc = dis[c];
    int s0 = rowptr[c], s1 = rowptr[c + 1];
    float acc = dc * __bfloat162float(h[(size_t)c * DH + t]);
    int i = s0;
    for (; i + 4 <= s1; i += 4) {
        int r0 = csr[i], r1 = csr[i + 1], r2 = csr[i + 2], r3 = csr[i + 3];
        float w0 = dis[r0], w1 = dis[r1], w2 = dis[r2], w3 = dis[r3];
        acc += w0 * __bfloat162float(h[(size_t)r0 * DH + t]);
        acc += w1 * __bfloat162float(h[(size_t)r1 * DH + t]);
        acc += w2 * __bfloat162float(h[(size_t)r2 * DH + t]);
        acc += w3 * __bfloat162float(h[(size_t)r3 * DH + t]);
    }
    for (; i < s1; i++) {
        int r = csr[i];
        acc += dis[r] * __bfloat162float(h[(size_t)r * DH + t]);
    }
    agg[(size_t)c * DH + t] = __float2bfloat16(dc * acc);
}

// ---------------- layer GEMM (MFMA): h = c0*(agg+x0) + c1*(agg@W1 + x0@W2) + LN sums ----------------
__global__ __launch_bounds__(256) void gemm_layer(
    const bf16* __restrict__ agg, const bf16* __restrict__ x0,
    const short* __restrict__ wt, size_t wbase,
    bf16* __restrict__ h, float* __restrict__ stats, float c0, float c1, int Nn)
{
    __shared__ short As[64 * 40];
    __shared__ short Bs[64 * 40];
    int t = threadIdx.x;
    int w = t >> 6, l = t & 63;
    int lr = l & 15, quad = l >> 4;
    int row0 = blockIdx.x * 64, col0 = blockIdx.y * 64;
    const short* aggS = (const short*)agg;
    const short* x0S = (const short*)x0;
    int srow = t >> 2;            // staging row 0..63
    int sc8 = (t & 3) * 8;        // staging col group
    f32x4 acc[4];
    #pragma unroll
    for (int nt = 0; nt < 4; nt++)
        #pragma unroll
        for (int j = 0; j < 4; j++) acc[nt][j] = 0.f;

    for (int k0 = 0; k0 < 2 * DH; k0 += 32) {
        const short* Asrc = (k0 < DH) ? aggS : x0S;
        int kb = k0 & (DH - 1);
        size_t wmat = wbase + ((k0 < DH) ? 0 : 65536);
        int gr = row0 + srow;
        short8 av = (short8)0;
        if (gr < Nn) av = *(const short8*)(Asrc + (size_t)gr * DH + kb + sc8);
        *(short8*)(As + srow * 40 + sc8) = av;
        short8 bv = *(const short8*)(wt + wmat + (size_t)(col0 + srow) * DH + kb + sc8);
        *(short8*)(Bs + srow * 40 + sc8) = bv;
        __syncthreads();
        short8 af = *(const short8*)(As + (w * 16 + lr) * 40 + quad * 8);
        #pragma unroll
        for (int nt = 0; nt < 4; nt++) {
            short8 bfv = *(const short8*)(Bs + (nt * 16 + lr) * 40 + quad * 8);
            acc[nt] = __builtin_amdgcn_mfma_f32_16x16x32_bf16(af, bfv, acc[nt], 0, 0, 0);
        }
        __syncthreads();
    }
    float lsum = 0.f, lsq = 0.f;
    #pragma unroll
    for (int nt = 0; nt < 4; nt++) {
        int gc = col0 + nt * 16 + lr;
        #pragma unroll
        for (int i = 0; i < 4; i++) {
            int gr = row0 + w * 16 + quad * 4 + i;
            if (gr < Nn) {
                size_t off = (size_t)gr * DH + gc;
                float e = __bfloat162float(agg[off]) + __bfloat162float(x0[off]);
                float v = c0 * e + c1 * acc[nt][i];
                h[off] = __float2bfloat16(v);
                lsum += v;
                lsq += v * v;
            }
        }
    }
    __syncthreads();
    float* red = (float*)As;
    red[t] = lsum;
    red[256 + t] = lsq;
    __syncthreads();
    for (int s = 128; s > 0; s >>= 1) {
        if (t < s) { red[t] += red[t + s]; red[256 + t] += red[256 + t + s]; }
        __syncthreads();
    }
    if (t == 0) {
        atomicAdd(&stats[0], red[0]);
        atomicAdd(&stats[1], red[256]);
    }
}

__global__ void k_finalize(float* __restrict__ stats, float invTotal) {
    float mu = stats[0] * invTotal;
    float var = stats[1] * invTotal - mu * mu;
    var = var > 0.f ? var : 0.f;
    stats[2] = mu;
    stats[3] = 1.0f / (sqrtf(var) + EPSLN);
    stats[0] = 0.f;
    stats[1] = 0.f;
}

// ---------------- layernorm apply + relu ----------------
__global__ __launch_bounds__(256) void k_apply(
    bf16* __restrict__ h, const float* __restrict__ stats,
    const void* __restrict__ g, const void* __restrict__ b, size_t loff,
    const int* __restrict__ flag, int total)
{
    int idx = blockIdx.x * 256 + threadIdx.x;
    if (idx >= total) return;
    const int isbf = *flag;
    float mu = stats[2], inv = stats[3];
    int j = idx & (DH - 1);
    float v = (__bfloat162float(h[idx]) - mu) * inv;
    v = fmaf(ldf(g, loff + j, isbf), v, ldf(b, loff + j, isbf));
    v = v > 0.f ? v : 0.f;
    h[idx] = __float2bfloat16(v);
}

// ---------------- GEMM 2 (SIMT): out = relu(h @ lin2_w + b2) ----------------
__global__ __launch_bounds__(256) void gemm_lin2(
    const bf16* __restrict__ A, const void* __restrict__ B,
    const void* __restrict__ bias, const int* __restrict__ flag,
    void* __restrict__ out, int Nn)
{
    const int BM = 64, BN = 64, BK = 16, AS = 17;
    __shared__ float As[BM * AS], Bs[BK * BN];
    const int isbf = *flag;
    int t = threadIdx.x;
    int tx = t & 15, ty = t >> 4;
    int row0 = blockIdx.x * BM, col0 = blockIdx.y * BN;
    float acc[4][4] = {};
    for (int k0 = 0; k0 < DH; k0 += BK) {
        #pragma unroll
        for (int i = 0; i < 4; i++) {
            int idx = t * 4 + i;
            int r = idx >> 4, c = idx & 15;
            int gr = row0 + r;
            As[r * AS + c] = (gr < Nn) ? __bfloat162float(A[(size_t)gr * DH + k0 + c]) : 0.f;
        }
        #pragma unroll
        for (int i = 0; i < 4; i++) {
            int idx = t * 4 + i;
            int r = idx >> 6, c = idx & 63;
            Bs[r * BN + c] = ldf(B, (size_t)(k0 + r) * DOUT + col0 + c, isbf);
        }
        __syncthreads();
        #pragma unroll
        for (int kk = 0; kk < BK; kk++) {
            float a[4], b[4];
            #pragma unroll
            for (int i = 0; i < 4; i++) a[i] = As[(ty * 4 + i) * AS + kk];
            #pragma unroll
            for (int j = 0; j < 4; j++) b[j] = Bs[kk * BN + tx * 4 + j];
            #pragma unroll
            for (int i = 0; i < 4; i++)
                #pragma unroll
                for (int j = 0; j < 4; j++) acc[i][j] = fmaf(a[i], b[j], acc[i][j]);
        }
        __syncthreads();
    }
    #pragma unroll
    for (int i = 0; i < 4; i++) {
        int gr = row0 + ty * 4 + i;
        if (gr >= Nn) continue;
        #pragma unroll
        for (int j = 0; j < 4; j++) {
            int gc = col0 + tx * 4 + j;
            float v = acc[i][j] + ldf(bias, gc, isbf);
            v = v > 0.f ? v : 0.f;
            size_t off = (size_t)gr * DOUT + gc;
            if (isbf) ((bf16*)out)[off] = __float2bfloat16(v);
            else      ((float*)out)[off] = v;
        }
    }
}

extern "C" void kernel_launch(void* const* d_in, const int* in_sizes, int n_in,
                              void* d_out, int out_size, void* d_ws, size_t ws_size,
                              hipStream_t stream) {
    const void* x      = d_in[0];
    const int*  ei     = (const int*)d_in[1];
    const void* lin1_w = d_in[2];
    const void* lin1_b = d_in[3];
    const void* conv_w1= d_in[4];
    const void* conv_w2= d_in[5];
    const void* gam    = d_in[6];
    const void* bet    = d_in[7];
    const void* lin2_w = d_in[8];
    const void* lin2_b = d_in[9];

    const int N = in_sizes[0] / DIN;
    const int E = in_sizes[1] / 2;
    const int* rows = ei;
    const int* cols = ei + E;
    const size_t NDH = (size_t)N * DH;
    const size_t Nr = ((size_t)N + 255) / 256 * 256;

    char* p = (char*)d_ws;
    auto alloc = [&](size_t bytes) { char* q = p; p += (bytes + 255) & ~(size_t)255; return q; };
    float* dis    = (float*)alloc(Nr * 4);
    float* stats  = (float*)alloc(1024);
    int*   flag   = (int*)(stats + 16);
    int*   cnt    = (int*)alloc(Nr * 4);
    int*   rowptr = (int*)alloc((Nr + 256) * 4);
    int*   cursor = (int*)alloc(Nr * 4);
    int*   bsum   = (int*)alloc(1024);
    int*   csr    = (int*)alloc((size_t)E * 4);
    short* wt     = (short*)alloc((size_t)16 * 65536 * 2);
    bf16*  agg    = (bf16*)alloc(NDH * 2);
    bf16*  x0     = (bf16*)alloc(NDH * 2);
    bf16*  h      = (bf16*)alloc(NDH * 2);

    dim3 blk(256);
    int nbN = (N + 255) / 256;
    dim3 gN(nbN);
    dim3 gE((E + 255) / 256);
    dim3 gMM((N + 63) / 64, DH / 64);
    dim3 gMM2((N + 63) / 64, DOUT / 64);
    dim3 gElem((unsigned)((NDH + 255) / 256));
    dim3 gTW(8, 8, 16);
    dim3 bTW(32, 8);

    k_detect<<<1, 256, 0, stream>>>((const unsigned int*)x, flag);
    k_init_cnt<<<gN, blk, 0, stream>>>(cnt, N);
    k_count<<<gE, blk, 0, stream>>>(cols, cnt, E);
    k_dis<<<gN, blk, 0, stream>>>(cnt, dis, N);
    k_scan1<<<gN, blk, 0, stream>>>(cnt, rowptr, bsum, N);
    k_scan2<<<1, 256, 0, stream>>>(bsum, nbN);
    k_scan3<<<gN, blk, 0, stream>>>(rowptr, bsum, N);
    k_cursor<<<gN, blk, 0, stream>>>(rowptr, cursor, N);
    k_fill<<<gE, blk, 0, stream>>>(rows, cols, cursor, csr, E);
    k_zero_stats<<<1, 64, 0, stream>>>(stats);
    k_transw<<<gTW, bTW, 0, stream>>>(conv_w1, conv_w2, flag, wt);

    gemm_lin1<<<gMM, blk, 0, stream>>>(x, lin1_w, lin1_b, flag, x0, h, N);

    const float invTotal = 1.0f / ((float)N * (float)DH);
    for (int l = 0; l < NLAYERS; l++) {
        float bl = logf(1.0f / (float)(l + 1) + 1.0f);
        float c0 = 0.5f * (1.0f - bl);
        float c1 = 0.5f * bl;
        k_gather<<<N, blk, 0, stream>>>(rowptr, csr, dis, h, agg);
        gemm_layer<<<gMM, blk, 0, stream>>>(agg, x0, wt, (size_t)l * 131072,
                                            h, stats, c0, c1, N);
        k_finalize<<<1, 1, 0, stream>>>(stats, invTotal);
        k_apply<<<gElem, blk, 0, stream>>>(h, stats, gam, bet, (size_t)l * DH,
                                           flag, (int)NDH);
    }
    gemm_lin2<<<gMM2, blk, 0, stream>>>(h, lin2_w, lin2_b, flag, d_out, N);
}

// Round 5
// 2197.906 us; speedup vs baseline: 3.8418x; 1.0058x over previous
//
#include <hip/hip_runtime.h>
#include <hip/hip_bf16.h>
#include <math.h>

#define DIN 128
#define DH 256
#define DOUT 128
#define NLAYERS 8
#define EPSLN 1e-5f

typedef __hip_bfloat16 bf16;
typedef __attribute__((ext_vector_type(8))) short short8;
typedef __attribute__((ext_vector_type(4))) short short4v;
typedef __attribute__((ext_vector_type(4))) float f32x4;

__device__ __forceinline__ float ldf(const void* p, size_t idx, int isbf) {
    if (isbf) return __bfloat162float(((const bf16*)p)[idx]);
    return ((const float*)p)[idx];
}
__device__ __forceinline__ short f2s(float v) {
    bf16 b = __float2bfloat16(v);
    return *reinterpret_cast<short*>(&b);
}
__device__ __forceinline__ float s2f(short s) {
    unsigned int u = ((unsigned int)(unsigned short)s) << 16;
    float f;
    __builtin_memcpy(&f, &u, 4);
    return f;
}

// ---------------- dtype probe ----------------
__global__ void k_detect(const unsigned int* __restrict__ xw, int* __restrict__ flag) {
    __shared__ int cnt;
    if (threadIdx.x == 0) cnt = 0;
    __syncthreads();
    unsigned int w = xw[threadIdx.x];
    int e = (w >> 7) & 0xFF;
    if (e >= 112 && e <= 140) atomicAdd(&cnt, 1);
    __syncthreads();
    if (threadIdx.x == 0) *flag = (cnt >= 128) ? 1 : 0;
}

// ---------------- degree + CSR build ----------------
__global__ void k_init_cnt(int* __restrict__ cnt, int N) {
    int i = blockIdx.x * blockDim.x + threadIdx.x;
    if (i < N) cnt[i] = 0;
}
__global__ void k_count(const int* __restrict__ cols, int* __restrict__ cnt, int E) {
    int e = blockIdx.x * blockDim.x + threadIdx.x;
    if (e < E) atomicAdd(&cnt[cols[e]], 1);
}
__global__ void k_dis(const int* __restrict__ cnt, float* __restrict__ dis, int N) {
    int i = blockIdx.x * blockDim.x + threadIdx.x;
    if (i < N) dis[i] = rsqrtf(1.0f + (float)cnt[i]);
}
__global__ void k_scan1(const int* __restrict__ cnt, int* __restrict__ rowptr,
                        int* __restrict__ bsum, int N) {
    __shared__ int s[256];
    int t = threadIdx.x;
    int i = blockIdx.x * 256 + t;
    s[t] = (i < N) ? cnt[i] : 0;
    __syncthreads();
    for (int off = 1; off < 256; off <<= 1) {
        int x = (t >= off) ? s[t - off] : 0;
        __syncthreads();
        s[t] += x;
        __syncthreads();
    }
    if (i < N) rowptr[i + 1] = s[t];
    if (t == 255) bsum[blockIdx.x] = s[255];
}
__global__ void k_scan2(int* __restrict__ bsum, int nb) {
    __shared__ int s[256];
    int t = threadIdx.x;
    s[t] = (t < nb) ? bsum[t] : 0;
    __syncthreads();
    for (int off = 1; off < 256; off <<= 1) {
        int x = (t >= off) ? s[t - off] : 0;
        __syncthreads();
        s[t] += x;
        __syncthreads();
    }
    if (t < nb) bsum[t] = s[t];
}
__global__ void k_scan3(int* __restrict__ rowptr, const int* __restrict__ bsum, int N) {
    int i = blockIdx.x * 256 + threadIdx.x;
    if (i == 0) rowptr[0] = 0;
    if (i < N && blockIdx.x > 0) rowptr[i + 1] += bsum[blockIdx.x - 1];
}
__global__ void k_cursor(const int* __restrict__ rowptr, int* __restrict__ cursor, int N) {
    int i = blockIdx.x * 256 + threadIdx.x;
    if (i < N) cursor[i] = rowptr[i];
}
__global__ void k_fill(const int* __restrict__ rows, const int* __restrict__ cols,
                       int* __restrict__ cursor, int* __restrict__ csr, int E) {
    int e = blockIdx.x * blockDim.x + threadIdx.x;
    if (e < E) {
        int c = cols[e], r = rows[e];
        int pos = atomicAdd(&cursor[c], 1);
        csr[pos] = r;
    }
}

__global__ void k_zero_stats(float* __restrict__ stats) {
    int t = threadIdx.x;
    if (t < 16) stats[t] = 0.0f;
}

// ------- weight fold+transpose: wt[l][n][k(512)] = c1*W{1,2}[k][n] + (k==n)*c0 -------
__global__ void k_transw2(const void* __restrict__ w1, const void* __restrict__ w2,
                          const int* __restrict__ flag, short* __restrict__ wt) {
    __shared__ float tile[32][33];
    int z = blockIdx.z;
    int lay = z >> 1, m = z & 1;
    const void* src = m ? w2 : w1;
    size_t sbase = (size_t)lay * 65536;
    short* dst = wt + (size_t)lay * 131072 + (size_t)m * 256;  // row stride 512
    float bl = logf(1.0f / (float)(lay + 1) + 1.0f);
    float c0 = 0.5f * (1.0f - bl);
    float c1 = 0.5f * bl;
    int isbf = *flag;
    int tx = threadIdx.x, ty = threadIdx.y;     // (32,8)
    int n0 = blockIdx.x * 32, k0 = blockIdx.y * 32;
    #pragma unroll
    for (int i = 0; i < 4; i++) {
        int k = k0 + ty + i * 8;
        tile[ty + i * 8][tx] = ldf(src, sbase + (size_t)k * 256 + n0 + tx, isbf);
    }
    __syncthreads();
    #pragma unroll
    for (int i = 0; i < 4; i++) {
        int n = n0 + ty + i * 8;
        int k = k0 + tx;
        float v = c1 * tile[tx][ty + i * 8];
        if (k == n) v += c0;
        dst[(size_t)n * 512 + k] = f2s(v);
    }
}

// ---------------- GEMM 1 (SIMT): x0 = relu(x @ lin1_w + b) ----------------
__global__ __launch_bounds__(256) void gemm_lin1(
    const void* __restrict__ A, const void* __restrict__ B,
    const void* __restrict__ bias, const int* __restrict__ flag,
    bf16* __restrict__ x0, int Nn)
{
    const int BM = 64, BN = 64, BK = 16, AS = 17;
    __shared__ float As[BM * AS], Bs[BK * BN];
    const int isbf = *flag;
    int t = threadIdx.x;
    int tx = t & 15, ty = t >> 4;
    int row0 = blockIdx.x * BM, col0 = blockIdx.y * BN;
    float acc[4][4] = {};
    for (int k0 = 0; k0 < DIN; k0 += BK) {
        #pragma unroll
        for (int i = 0; i < 4; i++) {
            int idx = t * 4 + i;
            int r = idx >> 4, c = idx & 15;
            int gr = row0 + r;
            As[r * AS + c] = (gr < Nn) ? ldf(A, (size_t)gr * DIN + k0 + c, isbf) : 0.f;
        }
        #pragma unroll
        for (int i = 0; i < 4; i++) {
            int idx = t * 4 + i;
            int r = idx >> 6, c = idx & 63;
            Bs[r * BN + c] = ldf(B, (size_t)(k0 + r) * DH + col0 + c, isbf);
        }
        __syncthreads();
        #pragma unroll
        for (int kk = 0; kk < BK; kk++) {
            float a[4], b[4];
            #pragma unroll
            for (int i = 0; i < 4; i++) a[i] = As[(ty * 4 + i) * AS + kk];
            #pragma unroll
            for (int j = 0; j < 4; j++) b[j] = Bs[kk * BN + tx * 4 + j];
            #pragma unroll
            for (int i = 0; i < 4; i++)
                #pragma unroll
                for (int j = 0; j < 4; j++) acc[i][j] = fmaf(a[i], b[j], acc[i][j]);
        }
        __syncthreads();
    }
    #pragma unroll
    for (int i = 0; i < 4; i++) {
        int gr = row0 + ty * 4 + i;
        if (gr >= Nn) continue;
        #pragma unroll
        for (int j = 0; j < 4; j++) {
            int gc = col0 + tx * 4 + j;
            float v = acc[i][j] + ldf(bias, gc, isbf);
            v = v > 0.f ? v : 0.f;
            x0[(size_t)gr * DH + gc] = __float2bfloat16(v);
        }
    }
}

// -------- CSR gather, wave-per-node, fused LN+relu transform of source h --------
// agg[c] = dc*( dc*T(h[c]) + sum_r dis[r]*T(h[r]) ),  T(v)=relu(cA*v+cB)
__global__ __launch_bounds__(256) void k_gather2(
    const int* __restrict__ rowptr, const int* __restrict__ csr,
    const float* __restrict__ dis, const bf16* __restrict__ hsrc,
    bf16* __restrict__ agg,
    const void* __restrict__ g, const void* __restrict__ b, size_t loff,
    const float* __restrict__ stats2, float invTotal, int useLN,
    const int* __restrict__ flag, int N)
{
    int gid = blockIdx.x * 256 + threadIdx.x;
    int node = gid >> 6;
    if (node >= N) return;
    int lane = gid & 63;
    int col = lane * 4;
    float cA[4], cB[4];
    if (useLN) {
        int isbf = *flag;
        float mu = stats2[0] * invTotal;
        float var = stats2[1] * invTotal - mu * mu;
        var = var > 0.f ? var : 0.f;
        float inv = 1.0f / (sqrtf(var) + EPSLN);
        #pragma unroll
        for (int j = 0; j < 4; j++) {
            float gg = ldf(g, loff + col + j, isbf);
            float bb = ldf(b, loff + col + j, isbf);
            cA[j] = gg * inv;
            cB[j] = fmaf(-gg * inv, mu, bb);
        }
    } else {
        #pragma unroll
        for (int j = 0; j < 4; j++) { cA[j] = 1.0f; cB[j] = 0.0f; }
    }
    const short* hs = (const short*)hsrc;
    float dc = dis[node];
    float acc[4];
    {
        short4v hv = *(const short4v*)(hs + (size_t)node * DH + col);
        #pragma unroll
        for (int j = 0; j < 4; j++) {
            float v = fmaf(cA[j], s2f(hv[j]), cB[j]);
            v = v > 0.f ? v : 0.f;
            acc[j] = dc * v;
        }
    }
    int i = rowptr[node], e1 = rowptr[node + 1];
    for (; i + 2 <= e1; i += 2) {
        int r0 = csr[i], r1 = csr[i + 1];
        float w0 = dis[r0], w1 = dis[r1];
        short4v v0 = *(const short4v*)(hs + (size_t)r0 * DH + col);
        short4v v1 = *(const short4v*)(hs + (size_t)r1 * DH + col);
        #pragma unroll
        for (int j = 0; j < 4; j++) {
            float a0 = fmaf(cA[j], s2f(v0[j]), cB[j]); a0 = a0 > 0.f ? a0 : 0.f;
            float a1 = fmaf(cA[j], s2f(v1[j]), cB[j]); a1 = a1 > 0.f ? a1 : 0.f;
            acc[j] = fmaf(w0, a0, acc[j]);
            acc[j] = fmaf(w1, a1, acc[j]);
        }
    }
    for (; i < e1; i++) {
        int r = csr[i];
        float wr = dis[r];
        short4v v0 = *(const short4v*)(hs + (size_t)r * DH + col);
        #pragma unroll
        for (int j = 0; j < 4; j++) {
            float a0 = fmaf(cA[j], s2f(v0[j]), cB[j]); a0 = a0 > 0.f ? a0 : 0.f;
            acc[j] = fmaf(wr, a0, acc[j]);
        }
    }
    short4v o;
    #pragma unroll
    for (int j = 0; j < 4; j++) o[j] = f2s(dc * acc[j]);
    *(short4v*)((short*)agg + (size_t)node * DH + col) = o;
}

// -------- layer GEMM (MFMA, register-direct, BN=256): h = agg@W1' + x0@W2' + LN sums --------
__global__ __launch_bounds__(256) void gemm_layer2(
    const bf16* __restrict__ agg, const bf16* __restrict__ x0,
    const short* __restrict__ wt, bf16* __restrict__ h,
    float* __restrict__ stats2, int Nn)
{
    __shared__ float red[512];
    int t = threadIdx.x;
    int w = t >> 6, l = t & 63;
    int lr = l & 15, quad = l >> 4;
    int row0 = blockIdx.x * 64;
    int arow = row0 + w * 16 + lr;
    bool rowok = arow < Nn;
    const short* aggS = (const short*)agg;
    const short* x0S  = (const short*)x0;
    size_t abase = (size_t)arow * DH + quad * 8;
    f32x4 acc[16];
    #pragma unroll
    for (int nt = 0; nt < 16; nt++)
        #pragma unroll
        for (int j = 0; j < 4; j++) acc[nt][j] = 0.f;

    for (int kb = 0; kb < 512; kb += 32) {
        const short* Asrc = (kb < DH) ? aggS : x0S;
        int ka = kb & (DH - 1);
        short8 af = (short8)0;
        if (rowok) af = *(const short8*)(Asrc + abase + ka);
        const short* wrow = wt + kb + quad * 8;
        #pragma unroll
        for (int nt = 0; nt < 16; nt++) {
            short8 bv = *(const short8*)(wrow + (size_t)(nt * 16 + lr) * 512);
            acc[nt] = __builtin_amdgcn_mfma_f32_16x16x32_bf16(af, bv, acc[nt], 0, 0, 0);
        }
    }
    float lsum = 0.f, lsq = 0.f;
    #pragma unroll
    for (int nt = 0; nt < 16; nt++) {
        int gc = nt * 16 + lr;
        #pragma unroll
        for (int i = 0; i < 4; i++) {
            int gr = row0 + w * 16 + quad * 4 + i;
            if (gr < Nn) {
                float v = acc[nt][i];
                h[(size_t)gr * DH + gc] = __float2bfloat16(v);
                lsum += v;
                lsq += v * v;
            }
        }
    }
    red[t] = lsum;
    red[256 + t] = lsq;
    __syncthreads();
    for (int s = 128; s > 0; s >>= 1) {
        if (t < s) { red[t] += red[t + s]; red[256 + t] += red[256 + t + s]; }
        __syncthreads();
    }
    if (t == 0) {
        atomicAdd(&stats2[0], red[0]);
        atomicAdd(&stats2[1], red[256]);
    }
}

// -------- GEMM 2 (SIMT): out = relu( T(h) @ lin2_w + b2 ), T = LN7+relu fused in load --------
__global__ __launch_bounds__(256) void gemm_lin2(
    const bf16* __restrict__ A, const void* __restrict__ B,
    const void* __restrict__ bias,
    const void* __restrict__ g, const void* __restrict__ bta, size_t loff,
    const float* __restrict__ stats2, float invTotal,
    const int* __restrict__ flag, void* __restrict__ out, int Nn)
{
    const int BM = 64, BN = 64, BK = 16, AS = 17;
    __shared__ float As[BM * AS], Bs[BK * BN];
    const int isbf = *flag;
    float mu = stats2[0] * invTotal;
    float var = stats2[1] * invTotal - mu * mu;
    var = var > 0.f ? var : 0.f;
    float inv = 1.0f / (sqrtf(var) + EPSLN);
    int t = threadIdx.x;
    int tx = t & 15, ty = t >> 4;
    int row0 = blockIdx.x * BM, col0 = blockIdx.y * BN;
    float acc[4][4] = {};
    for (int k0 = 0; k0 < DH; k0 += BK) {
        #pragma unroll
        for (int i = 0; i < 4; i++) {
            int idx = t * 4 + i;
            int r = idx >> 4, c = idx & 15;
            int gr = row0 + r;
            float v = 0.f;
            if (gr < Nn) {
                int kc = k0 + c;
                float gg = ldf(g, loff + kc, isbf);
                float bb = ldf(bta, loff + kc, isbf);
                float hv = __bfloat162float(A[(size_t)gr * DH + kc]);
                v = fmaf(gg * inv, hv, fmaf(-gg * inv, mu, bb));
                v = v > 0.f ? v : 0.f;
            }
            As[r * AS + c] = v;
        }
        #pragma unroll
        for (int i = 0; i < 4; i++) {
            int idx = t * 4 + i;
            int r = idx >> 6, c = idx & 63;
            Bs[r * BN + c] = ldf(B, (size_t)(k0 + r) * DOUT + col0 + c, isbf);
        }
        __syncthreads();
        #pragma unroll
        for (int kk = 0; kk < BK; kk++) {
            float a[4], b[4];
            #pragma unroll
            for (int i = 0; i < 4; i++) a[i] = As[(ty * 4 + i) * AS + kk];
            #pragma unroll
            for (int j = 0; j < 4; j++) b[j] = Bs[kk * BN + tx * 4 + j];
            #pragma unroll
            for (int i = 0; i < 4; i++)
                #pragma unroll
                for (int j = 0; j < 4; j++) acc[i][j] = fmaf(a[i], b[j], acc[i][j]);
        }
        __syncthreads();
    }
    #pragma unroll
    for (int i = 0; i < 4; i++) {
        int gr = row0 + ty * 4 + i;
        if (gr >= Nn) continue;
        #pragma unroll
        for (int j = 0; j < 4; j++) {
            int gc = col0 + tx * 4 + j;
            float v = acc[i][j] + ldf(bias, gc, isbf);
            v = v > 0.f ? v : 0.f;
            size_t off = (size_t)gr * DOUT + gc;
            if (isbf) ((bf16*)out)[off] = __float2bfloat16(v);
            else      ((float*)out)[off] = v;
        }
    }
}

extern "C" void kernel_launch(void* const* d_in, const int* in_sizes, int n_in,
                              void* d_out, int out_size, void* d_ws, size_t ws_size,
                              hipStream_t stream) {
    const void* x      = d_in[0];
    const int*  ei     = (const int*)d_in[1];
    const void* lin1_w = d_in[2];
    const void* lin1_b = d_in[3];
    const void* conv_w1= d_in[4];
    const void* conv_w2= d_in[5];
    const void* gam    = d_in[6];
    const void* bet    = d_in[7];
    const void* lin2_w = d_in[8];
    const void* lin2_b = d_in[9];

    const int N = in_sizes[0] / DIN;
    const int E = in_sizes[1] / 2;
    const int* rows = ei;
    const int* cols = ei + E;
    const size_t NDH = (size_t)N * DH;
    const size_t Nr = ((size_t)N + 255) / 256 * 256;

    char* p = (char*)d_ws;
    auto alloc = [&](size_t bytes) { char* q = p; p += (bytes + 255) & ~(size_t)255; return q; };
    float* dis    = (float*)alloc(Nr * 4);
    float* stats  = (float*)alloc(1024);          // 16 slots: 2 per layer
    int*   flag   = (int*)(stats + 16);
    int*   cnt    = (int*)alloc(Nr * 4);
    int*   rowptr = (int*)alloc((Nr + 256) * 4);
    int*   cursor = (int*)alloc(Nr * 4);
    int*   bsum   = (int*)alloc(1024);
    int*   csr    = (int*)alloc((size_t)E * 4);
    short* wt     = (short*)alloc((size_t)NLAYERS * 131072 * 2);  // 2 MB
    bf16*  agg    = (bf16*)alloc(NDH * 2);
    bf16*  x0     = (bf16*)alloc(NDH * 2);
    bf16*  h      = (bf16*)alloc(NDH * 2);

    dim3 blk(256);
    int nbN = (N + 255) / 256;
    dim3 gN(nbN);
    dim3 gE((E + 255) / 256);
    dim3 gMM1((N + 63) / 64, DH / 64);
    dim3 gMM2((N + 63) / 64, DOUT / 64);
    dim3 gL((N + 63) / 64);
    dim3 gG((N + 3) / 4);
    dim3 gTW(8, 8, 16);
    dim3 bTW(32, 8);

    k_detect<<<1, 256, 0, stream>>>((const unsigned int*)x, flag);
    k_init_cnt<<<gN, blk, 0, stream>>>(cnt, N);
    k_count<<<gE, blk, 0, stream>>>(cols, cnt, E);
    k_dis<<<gN, blk, 0, stream>>>(cnt, dis, N);
    k_scan1<<<gN, blk, 0, stream>>>(cnt, rowptr, bsum, N);
    k_scan2<<<1, 256, 0, stream>>>(bsum, nbN);
    k_scan3<<<gN, blk, 0, stream>>>(rowptr, bsum, N);
    k_cursor<<<gN, blk, 0, stream>>>(rowptr, cursor, N);
    k_fill<<<gE, blk, 0, stream>>>(rows, cols, cursor, csr, E);
    k_zero_stats<<<1, 64, 0, stream>>>(stats);
    k_transw2<<<gTW, bTW, 0, stream>>>(conv_w1, conv_w2, flag, wt);

    gemm_lin1<<<gMM1, blk, 0, stream>>>(x, lin1_w, lin1_b, flag, x0, N);

    const float invTotal = 1.0f / ((float)N * (float)DH);
    for (int l = 0; l < NLAYERS; l++) {
        const bf16* hsrc = (l == 0) ? x0 : h;
        size_t loff = (l == 0) ? 0 : (size_t)(l - 1) * DH;
        const float* st = (l == 0) ? stats : stats + 2 * (l - 1);
        k_gather2<<<gG, blk, 0, stream>>>(rowptr, csr, dis, hsrc, agg,
                                          gam, bet, loff, st, invTotal,
                                          l > 0 ? 1 : 0, flag, N);
        gemm_layer2<<<gL, blk, 0, stream>>>(agg, x0, wt + (size_t)l * 131072,
                                            h, stats + 2 * l, N);
    }
    gemm_lin2<<<gMM2, blk, 0, stream>>>(h, lin2_w, lin2_b, gam, bet,
                                        (size_t)(NLAYERS - 1) * DH,
                                        stats + 2 * (NLAYERS - 1), invTotal,
                                        flag, d_out, N);
}

// Round 6
// 1488.134 us; speedup vs baseline: 5.6742x; 1.4770x over previous
//
#include <hip/hip_runtime.h>
#include <hip/hip_bf16.h>
#include <math.h>

#define DIN 128
#define DH 256
#define DOUT 128
#define NLAYERS 8
#define EPSLN 1e-5f

typedef __hip_bfloat16 bf16;
typedef __attribute__((ext_vector_type(8))) short short8;
typedef __attribute__((ext_vector_type(4))) short short4v;
typedef __attribute__((ext_vector_type(4))) float f32x4;

__device__ __forceinline__ float ldf(const void* p, size_t idx, int isbf) {
    if (isbf) return __bfloat162float(((const bf16*)p)[idx]);
    return ((const float*)p)[idx];
}
__device__ __forceinline__ short f2s(float v) {
    bf16 b = __float2bfloat16(v);
    return *reinterpret_cast<short*>(&b);
}
__device__ __forceinline__ float s2f(short s) {
    unsigned int u = ((unsigned int)(unsigned short)s) << 16;
    float f;
    __builtin_memcpy(&f, &u, 4);
    return f;
}
__device__ __forceinline__ void gl_lds16(const void* g, void* l) {
    __builtin_amdgcn_global_load_lds(
        (const __attribute__((address_space(1))) unsigned int*)g,
        (__attribute__((address_space(3))) unsigned int*)l,
        16, 0, 0);
}

// ---------------- dtype probe ----------------
__global__ void k_detect(const unsigned int* __restrict__ xw, int* __restrict__ flag) {
    __shared__ int cnt;
    if (threadIdx.x == 0) cnt = 0;
    __syncthreads();
    unsigned int w = xw[threadIdx.x];
    int e = (w >> 7) & 0xFF;
    if (e >= 112 && e <= 140) atomicAdd(&cnt, 1);
    __syncthreads();
    if (threadIdx.x == 0) *flag = (cnt >= 128) ? 1 : 0;
}

// ---------------- degree + CSR build ----------------
__global__ void k_init_cnt(int* __restrict__ cnt, int N) {
    int i = blockIdx.x * blockDim.x + threadIdx.x;
    if (i < N) cnt[i] = 0;
}
__global__ void k_count(const int* __restrict__ cols, int* __restrict__ cnt, int E) {
    int e = blockIdx.x * blockDim.x + threadIdx.x;
    if (e < E) atomicAdd(&cnt[cols[e]], 1);
}
__global__ void k_dis(const int* __restrict__ cnt, float* __restrict__ dis, int N) {
    int i = blockIdx.x * blockDim.x + threadIdx.x;
    if (i < N) dis[i] = rsqrtf(1.0f + (float)cnt[i]);
}
__global__ void k_scan1(const int* __restrict__ cnt, int* __restrict__ rowptr,
                        int* __restrict__ bsum, int N) {
    __shared__ int s[256];
    int t = threadIdx.x;
    int i = blockIdx.x * 256 + t;
    s[t] = (i < N) ? cnt[i] : 0;
    __syncthreads();
    for (int off = 1; off < 256; off <<= 1) {
        int x = (t >= off) ? s[t - off] : 0;
        __syncthreads();
        s[t] += x;
        __syncthreads();
    }
    if (i < N) rowptr[i + 1] = s[t];
    if (t == 255) bsum[blockIdx.x] = s[255];
}
__global__ void k_scan2(int* __restrict__ bsum, int nb) {
    __shared__ int s[256];
    int t = threadIdx.x;
    s[t] = (t < nb) ? bsum[t] : 0;
    __syncthreads();
    for (int off = 1; off < 256; off <<= 1) {
        int x = (t >= off) ? s[t - off] : 0;
        __syncthreads();
        s[t] += x;
        __syncthreads();
    }
    if (t < nb) bsum[t] = s[t];
}
__global__ void k_scan3(int* __restrict__ rowptr, const int* __restrict__ bsum, int N) {
    int i = blockIdx.x * 256 + threadIdx.x;
    if (i == 0) rowptr[0] = 0;
    if (i < N && blockIdx.x > 0) rowptr[i + 1] += bsum[blockIdx.x - 1];
}
__global__ void k_cursor(const int* __restrict__ rowptr, int* __restrict__ cursor, int N) {
    int i = blockIdx.x * 256 + threadIdx.x;
    if (i < N) cursor[i] = rowptr[i];
}
__global__ void k_fill(const int* __restrict__ rows, const int* __restrict__ cols,
                       int* __restrict__ cursor, int* __restrict__ csr, int E) {
    int e = blockIdx.x * blockDim.x + threadIdx.x;
    if (e < E) {
        int c = cols[e], r = rows[e];
        int pos = atomicAdd(&cursor[c], 1);
        csr[pos] = r;
    }
}

__global__ void k_zero_stats(float* __restrict__ stats) {
    int t = threadIdx.x;
    if (t < 16) stats[t] = 0.0f;
}

// ------- weight fold+transpose: wt[l][n][k(512)] = c1*W{1,2}[k][n] + (k==n)*c0 -------
__global__ void k_transw2(const void* __restrict__ w1, const void* __restrict__ w2,
                          const int* __restrict__ flag, short* __restrict__ wt) {
    __shared__ float tile[32][33];
    int z = blockIdx.z;
    int lay = z >> 1, m = z & 1;
    const void* src = m ? w2 : w1;
    size_t sbase = (size_t)lay * 65536;
    short* dst = wt + (size_t)lay * 131072 + (size_t)m * 256;  // row stride 512
    float bl = logf(1.0f / (float)(lay + 1) + 1.0f);
    float c0 = 0.5f * (1.0f - bl);
    float c1 = 0.5f * bl;
    int isbf = *flag;
    int tx = threadIdx.x, ty = threadIdx.y;     // (32,8)
    int n0 = blockIdx.x * 32, k0 = blockIdx.y * 32;
    #pragma unroll
    for (int i = 0; i < 4; i++) {
        int k = k0 + ty + i * 8;
        tile[ty + i * 8][tx] = ldf(src, sbase + (size_t)k * 256 + n0 + tx, isbf);
    }
    __syncthreads();
    #pragma unroll
    for (int i = 0; i < 4; i++) {
        int n = n0 + ty + i * 8;
        int k = k0 + tx;
        float v = c1 * tile[tx][ty + i * 8];
        if (k == n) v += c0;
        dst[(size_t)n * 512 + k] = f2s(v);
    }
}

// ---------------- GEMM 1 (SIMT): x0 = relu(x @ lin1_w + b) ----------------
__global__ __launch_bounds__(256) void gemm_lin1(
    const void* __restrict__ A, const void* __restrict__ B,
    const void* __restrict__ bias, const int* __restrict__ flag,
    bf16* __restrict__ x0, int Nn)
{
    const int BM = 64, BN = 64, BK = 16, AS = 17;
    __shared__ float As[BM * AS], Bs[BK * BN];
    const int isbf = *flag;
    int t = threadIdx.x;
    int tx = t & 15, ty = t >> 4;
    int row0 = blockIdx.x * BM, col0 = blockIdx.y * BN;
    float acc[4][4] = {};
    for (int k0 = 0; k0 < DIN; k0 += BK) {
        #pragma unroll
        for (int i = 0; i < 4; i++) {
            int idx = t * 4 + i;
            int r = idx >> 4, c = idx & 15;
            int gr = row0 + r;
            As[r * AS + c] = (gr < Nn) ? ldf(A, (size_t)gr * DIN + k0 + c, isbf) : 0.f;
        }
        #pragma unroll
        for (int i = 0; i < 4; i++) {
            int idx = t * 4 + i;
            int r = idx >> 6, c = idx & 63;
            Bs[r * BN + c] = ldf(B, (size_t)(k0 + r) * DH + col0 + c, isbf);
        }
        __syncthreads();
        #pragma unroll
        for (int kk = 0; kk < BK; kk++) {
            float a[4], b[4];
            #pragma unroll
            for (int i = 0; i < 4; i++) a[i] = As[(ty * 4 + i) * AS + kk];
            #pragma unroll
            for (int j = 0; j < 4; j++) b[j] = Bs[kk * BN + tx * 4 + j];
            #pragma unroll
            for (int i = 0; i < 4; i++)
                #pragma unroll
                for (int j = 0; j < 4; j++) acc[i][j] = fmaf(a[i], b[j], acc[i][j]);
        }
        __syncthreads();
    }
    #pragma unroll
    for (int i = 0; i < 4; i++) {
        int gr = row0 + ty * 4 + i;
        if (gr >= Nn) continue;
        #pragma unroll
        for (int j = 0; j < 4; j++) {
            int gc = col0 + tx * 4 + j;
            float v = acc[i][j] + ldf(bias, gc, isbf);
            v = v > 0.f ? v : 0.f;
            x0[(size_t)gr * DH + gc] = __float2bfloat16(v);
        }
    }
}

// -------- CSR gather, wave-per-node, fused LN+relu transform of source h --------
__global__ __launch_bounds__(256) void k_gather2(
    const int* __restrict__ rowptr, const int* __restrict__ csr,
    const float* __restrict__ dis, const bf16* __restrict__ hsrc,
    bf16* __restrict__ agg,
    const void* __restrict__ g, const void* __restrict__ b, size_t loff,
    const float* __restrict__ stats2, float invTotal, int useLN,
    const int* __restrict__ flag, int N)
{
    int gid = blockIdx.x * 256 + threadIdx.x;
    int node = gid >> 6;
    if (node >= N) return;
    int lane = gid & 63;
    int col = lane * 4;
    float cA[4], cB[4];
    if (useLN) {
        int isbf = *flag;
        float mu = stats2[0] * invTotal;
        float var = stats2[1] * invTotal - mu * mu;
        var = var > 0.f ? var : 0.f;
        float inv = 1.0f / (sqrtf(var) + EPSLN);
        #pragma unroll
        for (int j = 0; j < 4; j++) {
            float gg = ldf(g, loff + col + j, isbf);
            float bb = ldf(b, loff + col + j, isbf);
            cA[j] = gg * inv;
            cB[j] = fmaf(-gg * inv, mu, bb);
        }
    } else {
        #pragma unroll
        for (int j = 0; j < 4; j++) { cA[j] = 1.0f; cB[j] = 0.0f; }
    }
    const short* hs = (const short*)hsrc;
    float dc = dis[node];
    float acc[4];
    {
        short4v hv = *(const short4v*)(hs + (size_t)node * DH + col);
        #pragma unroll
        for (int j = 0; j < 4; j++) {
            float v = fmaf(cA[j], s2f(hv[j]), cB[j]);
            v = v > 0.f ? v : 0.f;
            acc[j] = dc * v;
        }
    }
    int i = rowptr[node], e1 = rowptr[node + 1];
    for (; i + 2 <= e1; i += 2) {
        int r0 = csr[i], r1 = csr[i + 1];
        float w0 = dis[r0], w1 = dis[r1];
        short4v v0 = *(const short4v*)(hs + (size_t)r0 * DH + col);
        short4v v1 = *(const short4v*)(hs + (size_t)r1 * DH + col);
        #pragma unroll
        for (int j = 0; j < 4; j++) {
            float a0 = fmaf(cA[j], s2f(v0[j]), cB[j]); a0 = a0 > 0.f ? a0 : 0.f;
            float a1 = fmaf(cA[j], s2f(v1[j]), cB[j]); a1 = a1 > 0.f ? a1 : 0.f;
            acc[j] = fmaf(w0, a0, acc[j]);
            acc[j] = fmaf(w1, a1, acc[j]);
        }
    }
    for (; i < e1; i++) {
        int r = csr[i];
        float wr = dis[r];
        short4v v0 = *(const short4v*)(hs + (size_t)r * DH + col);
        #pragma unroll
        for (int j = 0; j < 4; j++) {
            float a0 = fmaf(cA[j], s2f(v0[j]), cB[j]); a0 = a0 > 0.f ? a0 : 0.f;
            acc[j] = fmaf(wr, a0, acc[j]);
        }
    }
    short4v o;
    #pragma unroll
    for (int j = 0; j < 4; j++) o[j] = f2s(dc * acc[j]);
    *(short4v*)((short*)agg + (size_t)node * DH + col) = o;
}

// ---- layer GEMM (MFMA, LDS-staged via global_load_lds): h = [agg|x0] @ W' + LN sums ----
// BM=128, BN=256(full), BK=32. 256 threads = 4 waves; wave w computes rows
// w*32..w*32+31 (two 16-row MFMA tiles) x all 256 cols (16 col tiles).
__global__ __launch_bounds__(256) void gemm_layer3(
    const bf16* __restrict__ agg, const bf16* __restrict__ x0,
    const short* __restrict__ wt, bf16* __restrict__ h,
    float* __restrict__ stats2, int Nn)
{
    __shared__ __align__(16) short Atile[128 * 32];   // 8 KB
    __shared__ __align__(16) short Btile[256 * 32];   // 16 KB
    int t = threadIdx.x;
    int w = t >> 6, lane = t & 63;
    int lr = lane & 15, quad = lane >> 4;
    int row0 = blockIdx.x * 128;
    int sub = t & 3;          // k-chunk (8 shorts) for staging
    int srow = t >> 2;        // staging row 0..63 (+64 per round)
    f32x4 acc[2][16];
    #pragma unroll
    for (int m = 0; m < 2; m++)
        #pragma unroll
        for (int nt = 0; nt < 16; nt++)
            #pragma unroll
            for (int j = 0; j < 4; j++) acc[m][nt][j] = 0.f;

    for (int kb = 0; kb < 512; kb += 32) {
        const short* Asrc = (const short*)((kb < DH) ? agg : x0);
        int ka = kb & (DH - 1);
        #pragma unroll
        for (int r = 0; r < 2; r++) {
            int row = srow + r * 64;
            int gr = row0 + row;
            if (gr >= Nn) gr = Nn - 1;   // clamp: values unused (store guarded)
            gl_lds16(Asrc + (size_t)gr * DH + ka + sub * 8,
                     Atile + (size_t)(t + r * 256) * 8);
        }
        #pragma unroll
        for (int r = 0; r < 4; r++) {
            int n = srow + r * 64;
            gl_lds16(wt + (size_t)n * 512 + kb + sub * 8,
                     Btile + (size_t)(t + r * 256) * 8);
        }
        __syncthreads();
        short8 a0 = *(const short8*)(Atile + (w * 32 + lr) * 32 + quad * 8);
        short8 a1 = *(const short8*)(Atile + (w * 32 + 16 + lr) * 32 + quad * 8);
        #pragma unroll
        for (int nt = 0; nt < 16; nt++) {
            short8 bv = *(const short8*)(Btile + (nt * 16 + lr) * 32 + quad * 8);
            acc[0][nt] = __builtin_amdgcn_mfma_f32_16x16x32_bf16(a0, bv, acc[0][nt], 0, 0, 0);
            acc[1][nt] = __builtin_amdgcn_mfma_f32_16x16x32_bf16(a1, bv, acc[1][nt], 0, 0, 0);
        }
        __syncthreads();
    }
    float lsum = 0.f, lsq = 0.f;
    #pragma unroll
    for (int m = 0; m < 2; m++) {
        #pragma unroll
        for (int nt = 0; nt < 16; nt++) {
            int gc = nt * 16 + lr;
            #pragma unroll
            for (int i = 0; i < 4; i++) {
                int gr = row0 + w * 32 + m * 16 + quad * 4 + i;
                if (gr < Nn) {
                    float v = acc[m][nt][i];
                    h[(size_t)gr * DH + gc] = __float2bfloat16(v);
                    lsum += v;
                    lsq += v * v;
                }
            }
        }
    }
    float* red = (float*)Btile;
    red[t] = lsum;
    red[256 + t] = lsq;
    __syncthreads();
    for (int s = 128; s > 0; s >>= 1) {
        if (t < s) { red[t] += red[t + s]; red[256 + t] += red[256 + t + s]; }
        __syncthreads();
    }
    if (t == 0) {
        atomicAdd(&stats2[0], red[0]);
        atomicAdd(&stats2[1], red[256]);
    }
}

// -------- GEMM 2 (SIMT): out = relu( T(h) @ lin2_w + b2 ), T = LN7+relu fused in load --------
__global__ __launch_bounds__(256) void gemm_lin2(
    const bf16* __restrict__ A, const void* __restrict__ B,
    const void* __restrict__ bias,
    const void* __restrict__ g, const void* __restrict__ bta, size_t loff,
    const float* __restrict__ stats2, float invTotal,
    const int* __restrict__ flag, void* __restrict__ out, int Nn)
{
    const int BM = 64, BN = 64, BK = 16, AS = 17;
    __shared__ float As[BM * AS], Bs[BK * BN];
    const int isbf = *flag;
    float mu = stats2[0] * invTotal;
    float var = stats2[1] * invTotal - mu * mu;
    var = var > 0.f ? var : 0.f;
    float inv = 1.0f / (sqrtf(var) + EPSLN);
    int t = threadIdx.x;
    int tx = t & 15, ty = t >> 4;
    int row0 = blockIdx.x * BM, col0 = blockIdx.y * BN;
    float acc[4][4] = {};
    for (int k0 = 0; k0 < DH; k0 += BK) {
        #pragma unroll
        for (int i = 0; i < 4; i++) {
            int idx = t * 4 + i;
            int r = idx >> 4, c = idx & 15;
            int gr = row0 + r;
            float v = 0.f;
            if (gr < Nn) {
                int kc = k0 + c;
                float gg = ldf(g, loff + kc, isbf);
                float bb = ldf(bta, loff + kc, isbf);
                float hv = __bfloat162float(A[(size_t)gr * DH + kc]);
                v = fmaf(gg * inv, hv, fmaf(-gg * inv, mu, bb));
                v = v > 0.f ? v : 0.f;
            }
            As[r * AS + c] = v;
        }
        #pragma unroll
        for (int i = 0; i < 4; i++) {
            int idx = t * 4 + i;
            int r = idx >> 6, c = idx & 63;
            Bs[r * BN + c] = ldf(B, (size_t)(k0 + r) * DOUT + col0 + c, isbf);
        }
        __syncthreads();
        #pragma unroll
        for (int kk = 0; kk < BK; kk++) {
            float a[4], b[4];
            #pragma unroll
            for (int i = 0; i < 4; i++) a[i] = As[(ty * 4 + i) * AS + kk];
            #pragma unroll
            for (int j = 0; j < 4; j++) b[j] = Bs[kk * BN + tx * 4 + j];
            #pragma unroll
            for (int i = 0; i < 4; i++)
                #pragma unroll
                for (int j = 0; j < 4; j++) acc[i][j] = fmaf(a[i], b[j], acc[i][j]);
        }
        __syncthreads();
    }
    #pragma unroll
    for (int i = 0; i < 4; i++) {
        int gr = row0 + ty * 4 + i;
        if (gr >= Nn) continue;
        #pragma unroll
        for (int j = 0; j < 4; j++) {
            int gc = col0 + tx * 4 + j;
            float v = acc[i][j] + ldf(bias, gc, isbf);
            v = v > 0.f ? v : 0.f;
            size_t off = (size_t)gr * DOUT + gc;
            if (isbf) ((bf16*)out)[off] = __float2bfloat16(v);
            else      ((float*)out)[off] = v;
        }
    }
}

extern "C" void kernel_launch(void* const* d_in, const int* in_sizes, int n_in,
                              void* d_out, int out_size, void* d_ws, size_t ws_size,
                              hipStream_t stream) {
    const void* x      = d_in[0];
    const int*  ei     = (const int*)d_in[1];
    const void* lin1_w = d_in[2];
    const void* lin1_b = d_in[3];
    const void* conv_w1= d_in[4];
    const void* conv_w2= d_in[5];
    const void* gam    = d_in[6];
    const void* bet    = d_in[7];
    const void* lin2_w = d_in[8];
    const void* lin2_b = d_in[9];

    const int N = in_sizes[0] / DIN;
    const int E = in_sizes[1] / 2;
    const int* rows = ei;
    const int* cols = ei + E;
    const size_t NDH = (size_t)N * DH;
    const size_t Nr = ((size_t)N + 255) / 256 * 256;

    char* p = (char*)d_ws;
    auto alloc = [&](size_t bytes) { char* q = p; p += (bytes + 255) & ~(size_t)255; return q; };
    float* dis    = (float*)alloc(Nr * 4);
    float* stats  = (float*)alloc(1024);          // 16 slots: 2 per layer
    int*   flag   = (int*)(stats + 16);
    int*   cnt    = (int*)alloc(Nr * 4);
    int*   rowptr = (int*)alloc((Nr + 256) * 4);
    int*   cursor = (int*)alloc(Nr * 4);
    int*   bsum   = (int*)alloc(1024);
    int*   csr    = (int*)alloc((size_t)E * 4);
    short* wt     = (short*)alloc((size_t)NLAYERS * 131072 * 2);  // 2 MB
    bf16*  agg    = (bf16*)alloc(NDH * 2);
    bf16*  x0     = (bf16*)alloc(NDH * 2);
    bf16*  h      = (bf16*)alloc(NDH * 2);

    dim3 blk(256);
    int nbN = (N + 255) / 256;
    dim3 gN(nbN);
    dim3 gE((E + 255) / 256);
    dim3 gMM1((N + 63) / 64, DH / 64);
    dim3 gMM2((N + 63) / 64, DOUT / 64);
    dim3 gL((N + 127) / 128);
    dim3 gG((N + 3) / 4);
    dim3 gTW(8, 8, 16);
    dim3 bTW(32, 8);

    k_detect<<<1, 256, 0, stream>>>((const unsigned int*)x, flag);
    k_init_cnt<<<gN, blk, 0, stream>>>(cnt, N);
    k_count<<<gE, blk, 0, stream>>>(cols, cnt, E);
    k_dis<<<gN, blk, 0, stream>>>(cnt, dis, N);
    k_scan1<<<gN, blk, 0, stream>>>(cnt, rowptr, bsum, N);
    k_scan2<<<1, 256, 0, stream>>>(bsum, nbN);
    k_scan3<<<gN, blk, 0, stream>>>(rowptr, bsum, N);
    k_cursor<<<gN, blk, 0, stream>>>(rowptr, cursor, N);
    k_fill<<<gE, blk, 0, stream>>>(rows, cols, cursor, csr, E);
    k_zero_stats<<<1, 64, 0, stream>>>(stats);
    k_transw2<<<gTW, bTW, 0, stream>>>(conv_w1, conv_w2, flag, wt);

    gemm_lin1<<<gMM1, blk, 0, stream>>>(x, lin1_w, lin1_b, flag, x0, N);

    const float invTotal = 1.0f / ((float)N * (float)DH);
    for (int l = 0; l < NLAYERS; l++) {
        const bf16* hsrc = (l == 0) ? x0 : h;
        size_t loff = (l == 0) ? 0 : (size_t)(l - 1) * DH;
        const float* st = (l == 0) ? stats : stats + 2 * (l - 1);
        k_gather2<<<gG, blk, 0, stream>>>(rowptr, csr, dis, hsrc, agg,
                                          gam, bet, loff, st, invTotal,
                                          l > 0 ? 1 : 0, flag, N);
        gemm_layer3<<<gL, blk, 0, stream>>>(agg, x0, wt + (size_t)l * 131072,
                                            h, stats + 2 * l, N);
    }
    gemm_lin2<<<gMM2, blk, 0, stream>>>(h, lin2_w, lin2_b, gam, bet,
                                        (size_t)(NLAYERS - 1) * DH,
                                        stats + 2 * (NLAYERS - 1), invTotal,
                                        flag, d_out, N);
}

// Round 7
// 1276.499 us; speedup vs baseline: 6.6150x; 1.1658x over previous
//
#include <hip/hip_runtime.h>
#include <hip/hip_bf16.h>
#include <math.h>

#define DIN 128
#define DH 256
#define DOUT 128
#define NLAYERS 8
#define EPSLN 1e-5f

typedef __hip_bfloat16 bf16;
typedef __attribute__((ext_vector_type(8))) short short8;
typedef __attribute__((ext_vector_type(4))) short short4v;
typedef __attribute__((ext_vector_type(4))) float f32x4;

__device__ __forceinline__ float ldf(const void* p, size_t idx, int isbf) {
    if (isbf) return __bfloat162float(((const bf16*)p)[idx]);
    return ((const float*)p)[idx];
}
__device__ __forceinline__ short f2s(float v) {
    bf16 b = __float2bfloat16(v);
    return *reinterpret_cast<short*>(&b);
}
__device__ __forceinline__ float s2f(short s) {
    unsigned int u = ((unsigned int)(unsigned short)s) << 16;
    float f;
    __builtin_memcpy(&f, &u, 4);
    return f;
}
__device__ __forceinline__ void gl_lds16(const void* g, void* l) {
    __builtin_amdgcn_global_load_lds(
        (const __attribute__((address_space(1))) unsigned int*)g,
        (__attribute__((address_space(3))) unsigned int*)l,
        16, 0, 0);
}

// ---------------- dtype probe ----------------
__global__ void k_detect(const unsigned int* __restrict__ xw, int* __restrict__ flag) {
    __shared__ int cnt;
    if (threadIdx.x == 0) cnt = 0;
    __syncthreads();
    unsigned int w = xw[threadIdx.x];
    int e = (w >> 7) & 0xFF;
    if (e >= 112 && e <= 140) atomicAdd(&cnt, 1);
    __syncthreads();
    if (threadIdx.x == 0) *flag = (cnt >= 128) ? 1 : 0;
}

// ---------------- degree + CSR build ----------------
__global__ void k_init_cnt(int* __restrict__ cnt, int N) {
    int i = blockIdx.x * blockDim.x + threadIdx.x;
    if (i < N) cnt[i] = 0;
}
__global__ void k_count(const int* __restrict__ cols, int* __restrict__ cnt, int E) {
    int e = blockIdx.x * blockDim.x + threadIdx.x;
    if (e < E) atomicAdd(&cnt[cols[e]], 1);
}
__global__ void k_dis(const int* __restrict__ cnt, float* __restrict__ dis, int N) {
    int i = blockIdx.x * blockDim.x + threadIdx.x;
    if (i < N) dis[i] = rsqrtf(1.0f + (float)cnt[i]);
}
__global__ void k_scan1(const int* __restrict__ cnt, int* __restrict__ rowptr,
                        int* __restrict__ bsum, int N) {
    __shared__ int s[256];
    int t = threadIdx.x;
    int i = blockIdx.x * 256 + t;
    s[t] = (i < N) ? cnt[i] : 0;
    __syncthreads();
    for (int off = 1; off < 256; off <<= 1) {
        int x = (t >= off) ? s[t - off] : 0;
        __syncthreads();
        s[t] += x;
        __syncthreads();
    }
    if (i < N) rowptr[i + 1] = s[t];
    if (t == 255) bsum[blockIdx.x] = s[255];
}
__global__ void k_scan2(int* __restrict__ bsum, int nb) {
    __shared__ int s[256];
    int t = threadIdx.x;
    s[t] = (t < nb) ? bsum[t] : 0;
    __syncthreads();
    for (int off = 1; off < 256; off <<= 1) {
        int x = (t >= off) ? s[t - off] : 0;
        __syncthreads();
        s[t] += x;
        __syncthreads();
    }
    if (t < nb) bsum[t] = s[t];
}
__global__ void k_scan3(int* __restrict__ rowptr, const int* __restrict__ bsum, int N) {
    int i = blockIdx.x * 256 + threadIdx.x;
    if (i == 0) rowptr[0] = 0;
    if (i < N && blockIdx.x > 0) rowptr[i + 1] += bsum[blockIdx.x - 1];
}
__global__ void k_cursor(const int* __restrict__ rowptr, int* __restrict__ cursor, int N) {
    int i = blockIdx.x * 256 + threadIdx.x;
    if (i < N) cursor[i] = rowptr[i];
}
__global__ void k_fill(const int* __restrict__ rows, const int* __restrict__ cols,
                       int* __restrict__ cursor, int* __restrict__ csr, int E) {
    int e = blockIdx.x * blockDim.x + threadIdx.x;
    if (e < E) {
        int c = cols[e], r = rows[e];
        int pos = atomicAdd(&cursor[c], 1);
        csr[pos] = r;
    }
}

__global__ void k_zero_stats(float* __restrict__ stats) {
    int t = threadIdx.x;
    if (t < 16) stats[t] = 0.0f;
}

// ------- conv weight fold+transpose: wt[l][n][k(512)] = c1*W{1,2}[k][n] + (k==n)*c0 -------
__global__ void k_transw2(const void* __restrict__ w1, const void* __restrict__ w2,
                          const int* __restrict__ flag, short* __restrict__ wt) {
    __shared__ float tile[32][33];
    int z = blockIdx.z;
    int lay = z >> 1, m = z & 1;
    const void* src = m ? w2 : w1;
    size_t sbase = (size_t)lay * 65536;
    short* dst = wt + (size_t)lay * 131072 + (size_t)m * 256;  // row stride 512
    float bl = logf(1.0f / (float)(lay + 1) + 1.0f);
    float c0 = 0.5f * (1.0f - bl);
    float c1 = 0.5f * bl;
    int isbf = *flag;
    int tx = threadIdx.x, ty = threadIdx.y;     // (32,8)
    int n0 = blockIdx.x * 32, k0 = blockIdx.y * 32;
    #pragma unroll
    for (int i = 0; i < 4; i++) {
        int k = k0 + ty + i * 8;
        tile[ty + i * 8][tx] = ldf(src, sbase + (size_t)k * 256 + n0 + tx, isbf);
    }
    __syncthreads();
    #pragma unroll
    for (int i = 0; i < 4; i++) {
        int n = n0 + ty + i * 8;
        int k = k0 + tx;
        float v = c1 * tile[tx][ty + i * 8];
        if (k == n) v += c0;
        dst[(size_t)n * 512 + k] = f2s(v);
    }
}

// ------- generic transpose to bf16: dst[n][K] = src[k][n], src is [K, Nc] -------
__global__ void k_transw_lin(const void* __restrict__ src, const int* __restrict__ flag,
                             short* __restrict__ dst, int K, int Nc) {
    __shared__ float tile[32][33];
    int isbf = *flag;
    int tx = threadIdx.x, ty = threadIdx.y;     // (32,8)
    int n0 = blockIdx.x * 32, k0 = blockIdx.y * 32;
    #pragma unroll
    for (int i = 0; i < 4; i++) {
        int k = k0 + ty + i * 8;
        tile[ty + i * 8][tx] = ldf(src, (size_t)k * Nc + n0 + tx, isbf);
    }
    __syncthreads();
    #pragma unroll
    for (int i = 0; i < 4; i++) {
        int n = n0 + ty + i * 8;
        dst[(size_t)n * K + k0 + tx] = f2s(tile[tx][ty + i * 8]);
    }
}

// ------- x conversion to guaranteed-bf16 -------
__global__ void k_convx(const void* __restrict__ x, const int* __restrict__ flag,
                        short* __restrict__ xb, int total) {
    int i = blockIdx.x * 256 + threadIdx.x;
    if (i < total) xb[i] = f2s(ldf(x, i, *flag));
}

// ---- generic MFMA GEMM: out = relu(A @ wt^T + bias). A [M,KK] bf16, wt [BN,KK] bf16 ----
// BM=128, full-width BN. FINAL=1 -> out dtype per flag; else bf16.
template<int BN, int KK, int FINAL>
__global__ __launch_bounds__(256) void gemm_mfma(
    const short* __restrict__ A, const short* __restrict__ wt,
    const void* __restrict__ bias, const int* __restrict__ flag,
    void* __restrict__ outp, int Nn)
{
    constexpr int NT = BN / 16;
    __shared__ __align__(16) short Atile[128 * 32];
    __shared__ __align__(16) short Btile[BN * 32];
    int t = threadIdx.x;
    int w = t >> 6, lane = t & 63;
    int lr = lane & 15, quad = lane >> 4;
    int row0 = blockIdx.x * 128;
    int sub = t & 3;
    int srow = t >> 2;
    f32x4 acc[2][NT];
    #pragma unroll
    for (int m = 0; m < 2; m++)
        #pragma unroll
        for (int nt = 0; nt < NT; nt++)
            #pragma unroll
            for (int j = 0; j < 4; j++) acc[m][nt][j] = 0.f;

    for (int kb = 0; kb < KK; kb += 32) {
        #pragma unroll
        for (int r = 0; r < 2; r++) {
            int gr = row0 + srow + r * 64;
            if (gr >= Nn) gr = Nn - 1;
            gl_lds16(A + (size_t)gr * KK + kb + sub * 8,
                     Atile + (size_t)(t + r * 256) * 8);
        }
        #pragma unroll
        for (int r = 0; r < BN / 64; r++) {
            int n = srow + r * 64;
            gl_lds16(wt + (size_t)n * KK + kb + sub * 8,
                     Btile + (size_t)(t + r * 256) * 8);
        }
        __syncthreads();
        short8 a0 = *(const short8*)(Atile + (w * 32 + lr) * 32 + quad * 8);
        short8 a1 = *(const short8*)(Atile + (w * 32 + 16 + lr) * 32 + quad * 8);
        #pragma unroll
        for (int nt = 0; nt < NT; nt++) {
            short8 bv = *(const short8*)(Btile + (nt * 16 + lr) * 32 + quad * 8);
            acc[0][nt] = __builtin_amdgcn_mfma_f32_16x16x32_bf16(a0, bv, acc[0][nt], 0, 0, 0);
            acc[1][nt] = __builtin_amdgcn_mfma_f32_16x16x32_bf16(a1, bv, acc[1][nt], 0, 0, 0);
        }
        __syncthreads();
    }
    const int isbf = *flag;
    #pragma unroll
    for (int m = 0; m < 2; m++) {
        #pragma unroll
        for (int nt = 0; nt < NT; nt++) {
            int gc = nt * 16 + lr;
            float bb = ldf(bias, gc, isbf);
            #pragma unroll
            for (int i = 0; i < 4; i++) {
                int gr = row0 + w * 32 + m * 16 + quad * 4 + i;
                if (gr < Nn) {
                    float v = acc[m][nt][i] + bb;
                    v = v > 0.f ? v : 0.f;
                    size_t off = (size_t)gr * BN + gc;
                    if (FINAL) {
                        if (isbf) ((bf16*)outp)[off] = __float2bfloat16(v);
                        else      ((float*)outp)[off] = v;
                    } else {
                        ((bf16*)outp)[off] = __float2bfloat16(v);
                    }
                }
            }
        }
    }
}

// -------- CSR gather, wave-per-node, fused LN+relu transform of source h --------
__global__ __launch_bounds__(256) void k_gather2(
    const int* __restrict__ rowptr, const int* __restrict__ csr,
    const float* __restrict__ dis, const bf16* __restrict__ hsrc,
    bf16* __restrict__ agg,
    const void* __restrict__ g, const void* __restrict__ b, size_t loff,
    const float* __restrict__ stats2, float invTotal, int useLN,
    const int* __restrict__ flag, int N)
{
    int gid = blockIdx.x * 256 + threadIdx.x;
    int node = gid >> 6;
    if (node >= N) return;
    int lane = gid & 63;
    int col = lane * 4;
    float cA[4], cB[4];
    if (useLN) {
        int isbf = *flag;
        float mu = stats2[0] * invTotal;
        float var = stats2[1] * invTotal - mu * mu;
        var = var > 0.f ? var : 0.f;
        float inv = 1.0f / (sqrtf(var) + EPSLN);
        #pragma unroll
        for (int j = 0; j < 4; j++) {
            float gg = ldf(g, loff + col + j, isbf);
            float bb = ldf(b, loff + col + j, isbf);
            cA[j] = gg * inv;
            cB[j] = fmaf(-gg * inv, mu, bb);
        }
    } else {
        #pragma unroll
        for (int j = 0; j < 4; j++) { cA[j] = 1.0f; cB[j] = 0.0f; }
    }
    const short* hs = (const short*)hsrc;
    float dc = dis[node];
    float acc[4], acc2[4];
    {
        short4v hv = *(const short4v*)(hs + (size_t)node * DH + col);
        #pragma unroll
        for (int j = 0; j < 4; j++) {
            float v = fmaf(cA[j], s2f(hv[j]), cB[j]);
            v = v > 0.f ? v : 0.f;
            acc[j] = dc * v;
            acc2[j] = 0.f;
        }
    }
    int i = rowptr[node], e1 = rowptr[node + 1];
    for (; i + 4 <= e1; i += 4) {
        int r0 = csr[i], r1 = csr[i + 1], r2 = csr[i + 2], r3 = csr[i + 3];
        float w0 = dis[r0], w1 = dis[r1], w2 = dis[r2], w3 = dis[r3];
        short4v v0 = *(const short4v*)(hs + (size_t)r0 * DH + col);
        short4v v1 = *(const short4v*)(hs + (size_t)r1 * DH + col);
        short4v v2 = *(const short4v*)(hs + (size_t)r2 * DH + col);
        short4v v3 = *(const short4v*)(hs + (size_t)r3 * DH + col);
        #pragma unroll
        for (int j = 0; j < 4; j++) {
            float a0 = fmaf(cA[j], s2f(v0[j]), cB[j]); a0 = a0 > 0.f ? a0 : 0.f;
            float a1 = fmaf(cA[j], s2f(v1[j]), cB[j]); a1 = a1 > 0.f ? a1 : 0.f;
            float a2 = fmaf(cA[j], s2f(v2[j]), cB[j]); a2 = a2 > 0.f ? a2 : 0.f;
            float a3 = fmaf(cA[j], s2f(v3[j]), cB[j]); a3 = a3 > 0.f ? a3 : 0.f;
            acc[j]  = fmaf(w0, a0, acc[j]);
            acc2[j] = fmaf(w1, a1, acc2[j]);
            acc[j]  = fmaf(w2, a2, acc[j]);
            acc2[j] = fmaf(w3, a3, acc2[j]);
        }
    }
    for (; i < e1; i++) {
        int r = csr[i];
        float wr = dis[r];
        short4v v0 = *(const short4v*)(hs + (size_t)r * DH + col);
        #pragma unroll
        for (int j = 0; j < 4; j++) {
            float a0 = fmaf(cA[j], s2f(v0[j]), cB[j]); a0 = a0 > 0.f ? a0 : 0.f;
            acc[j] = fmaf(wr, a0, acc[j]);
        }
    }
    short4v o;
    #pragma unroll
    for (int j = 0; j < 4; j++) o[j] = f2s(dc * (acc[j] + acc2[j]));
    *(short4v*)((short*)agg + (size_t)node * DH + col) = o;
}

// ---- layer GEMM (MFMA, LDS-staged): h = [agg|x0] @ W' + LN sums ----
__global__ __launch_bounds__(256) void gemm_layer3(
    const bf16* __restrict__ agg, const bf16* __restrict__ x0,
    const short* __restrict__ wt, bf16* __restrict__ h,
    float* __restrict__ stats2, int Nn)
{
    __shared__ __align__(16) short Atile[128 * 32];
    __shared__ __align__(16) short Btile[256 * 32];
    int t = threadIdx.x;
    int w = t >> 6, lane = t & 63;
    int lr = lane & 15, quad = lane >> 4;
    int row0 = blockIdx.x * 128;
    int sub = t & 3;
    int srow = t >> 2;
    f32x4 acc[2][16];
    #pragma unroll
    for (int m = 0; m < 2; m++)
        #pragma unroll
        for (int nt = 0; nt < 16; nt++)
            #pragma unroll
            for (int j = 0; j < 4; j++) acc[m][nt][j] = 0.f;

    for (int kb = 0; kb < 512; kb += 32) {
        const short* Asrc = (const short*)((kb < DH) ? agg : x0);
        int ka = kb & (DH - 1);
        #pragma unroll
        for (int r = 0; r < 2; r++) {
            int gr = row0 + srow + r * 64;
            if (gr >= Nn) gr = Nn - 1;
            gl_lds16(Asrc + (size_t)gr * DH + ka + sub * 8,
                     Atile + (size_t)(t + r * 256) * 8);
        }
        #pragma unroll
        for (int r = 0; r < 4; r++) {
            int n = srow + r * 64;
            gl_lds16(wt + (size_t)n * 512 + kb + sub * 8,
                     Btile + (size_t)(t + r * 256) * 8);
        }
        __syncthreads();
        short8 a0 = *(const short8*)(Atile + (w * 32 + lr) * 32 + quad * 8);
        short8 a1 = *(const short8*)(Atile + (w * 32 + 16 + lr) * 32 + quad * 8);
        #pragma unroll
        for (int nt = 0; nt < 16; nt++) {
            short8 bv = *(const short8*)(Btile + (nt * 16 + lr) * 32 + quad * 8);
            acc[0][nt] = __builtin_amdgcn_mfma_f32_16x16x32_bf16(a0, bv, acc[0][nt], 0, 0, 0);
            acc[1][nt] = __builtin_amdgcn_mfma_f32_16x16x32_bf16(a1, bv, acc[1][nt], 0, 0, 0);
        }
        __syncthreads();
    }
    float lsum = 0.f, lsq = 0.f;
    #pragma unroll
    for (int m = 0; m < 2; m++) {
        #pragma unroll
        for (int nt = 0; nt < 16; nt++) {
            int gc = nt * 16 + lr;
            #pragma unroll
            for (int i = 0; i < 4; i++) {
                int gr = row0 + w * 32 + m * 16 + quad * 4 + i;
                if (gr < Nn) {
                    float v = acc[m][nt][i];
                    h[(size_t)gr * DH + gc] = __float2bfloat16(v);
                    lsum += v;
                    lsq += v * v;
                }
            }
        }
    }
    float* red = (float*)Btile;
    red[t] = lsum;
    red[256 + t] = lsq;
    __syncthreads();
    for (int s = 128; s > 0; s >>= 1) {
        if (t < s) { red[t] += red[t + s]; red[256 + t] += red[256 + t + s]; }
        __syncthreads();
    }
    if (t == 0) {
        atomicAdd(&stats2[0], red[0]);
        atomicAdd(&stats2[1], red[256]);
    }
}

// ------- final LN+relu applied in place to h (layer-8 stats) -------
__global__ __launch_bounds__(256) void k_applyT(
    bf16* __restrict__ h, const float* __restrict__ stats2, float invTotal,
    const void* __restrict__ g, const void* __restrict__ b, size_t loff,
    const int* __restrict__ flag, int total)
{
    int idx = blockIdx.x * 256 + threadIdx.x;
    if (idx >= total) return;
    const int isbf = *flag;
    float mu = stats2[0] * invTotal;
    float var = stats2[1] * invTotal - mu * mu;
    var = var > 0.f ? var : 0.f;
    float inv = 1.0f / (sqrtf(var) + EPSLN);
    int j = idx & (DH - 1);
    float gg = ldf(g, loff + j, isbf);
    float bb = ldf(b, loff + j, isbf);
    float v = fmaf(gg * inv, __bfloat162float(h[idx]), fmaf(-gg * inv, mu, bb));
    v = v > 0.f ? v : 0.f;
    h[idx] = __float2bfloat16(v);
}

extern "C" void kernel_launch(void* const* d_in, const int* in_sizes, int n_in,
                              void* d_out, int out_size, void* d_ws, size_t ws_size,
                              hipStream_t stream) {
    const void* x      = d_in[0];
    const int*  ei     = (const int*)d_in[1];
    const void* lin1_w = d_in[2];
    const void* lin1_b = d_in[3];
    const void* conv_w1= d_in[4];
    const void* conv_w2= d_in[5];
    const void* gam    = d_in[6];
    const void* bet    = d_in[7];
    const void* lin2_w = d_in[8];
    const void* lin2_b = d_in[9];

    const int N = in_sizes[0] / DIN;
    const int E = in_sizes[1] / 2;
    const int* rows = ei;
    const int* cols = ei + E;
    const size_t NDH = (size_t)N * DH;
    const size_t Nr = ((size_t)N + 255) / 256 * 256;

    char* p = (char*)d_ws;
    auto alloc = [&](size_t bytes) { char* q = p; p += (bytes + 255) & ~(size_t)255; return q; };
    float* dis    = (float*)alloc(Nr * 4);
    float* stats  = (float*)alloc(1024);          // 16 slots: 2 per layer
    int*   flag   = (int*)(stats + 16);
    int*   cnt    = (int*)alloc(Nr * 4);
    int*   rowptr = (int*)alloc((Nr + 256) * 4);
    int*   cursor = (int*)alloc(Nr * 4);
    int*   bsum   = (int*)alloc(1024);
    int*   csr    = (int*)alloc((size_t)E * 4);
    short* wt     = (short*)alloc((size_t)NLAYERS * 131072 * 2);  // 2 MB folded conv weights
    short* w1t    = (short*)alloc((size_t)DH * DIN * 2);          // lin1^T
    short* w2t    = (short*)alloc((size_t)DOUT * DH * 2);         // lin2^T
    short* xb     = (short*)alloc((size_t)N * DIN * 2);           // x as bf16
    bf16*  agg    = (bf16*)alloc(NDH * 2);
    bf16*  x0     = (bf16*)alloc(NDH * 2);
    bf16*  h      = (bf16*)alloc(NDH * 2);

    dim3 blk(256);
    int nbN = (N + 255) / 256;
    dim3 gN(nbN);
    dim3 gE((E + 255) / 256);
    dim3 gB((N + 127) / 128);
    dim3 gG((N + 3) / 4);
    dim3 gElem((unsigned)((NDH + 255) / 256));
    dim3 gTW(8, 8, 16);
    dim3 bTW(32, 8);

    k_detect<<<1, 256, 0, stream>>>((const unsigned int*)x, flag);
    k_init_cnt<<<gN, blk, 0, stream>>>(cnt, N);
    k_count<<<gE, blk, 0, stream>>>(cols, cnt, E);
    k_dis<<<gN, blk, 0, stream>>>(cnt, dis, N);
    k_scan1<<<gN, blk, 0, stream>>>(cnt, rowptr, bsum, N);
    k_scan2<<<1, 256, 0, stream>>>(bsum, nbN);
    k_scan3<<<gN, blk, 0, stream>>>(rowptr, bsum, N);
    k_cursor<<<gN, blk, 0, stream>>>(rowptr, cursor, N);
    k_fill<<<gE, blk, 0, stream>>>(rows, cols, cursor, csr, E);
    k_zero_stats<<<1, 64, 0, stream>>>(stats);
    k_transw2<<<gTW, bTW, 0, stream>>>(conv_w1, conv_w2, flag, wt);
    k_transw_lin<<<dim3(DH / 32, DIN / 32), bTW, 0, stream>>>(lin1_w, flag, w1t, DIN, DH);
    k_transw_lin<<<dim3(DOUT / 32, DH / 32), bTW, 0, stream>>>(lin2_w, flag, w2t, DH, DOUT);
    k_convx<<<dim3((unsigned)(((size_t)N * DIN + 255) / 256)), blk, 0, stream>>>(x, flag, xb, N * DIN);

    // lin1: x0 = relu(x @ lin1_w + b)
    gemm_mfma<DH, DIN, 0><<<gB, blk, 0, stream>>>(xb, w1t, lin1_b, flag, x0, N);

    const float invTotal = 1.0f / ((float)N * (float)DH);
    for (int l = 0; l < NLAYERS; l++) {
        const bf16* hsrc = (l == 0) ? x0 : h;
        size_t loff = (l == 0) ? 0 : (size_t)(l - 1) * DH;
        const float* st = (l == 0) ? stats : stats + 2 * (l - 1);
        k_gather2<<<gG, blk, 0, stream>>>(rowptr, csr, dis, hsrc, agg,
                                          gam, bet, loff, st, invTotal,
                                          l > 0 ? 1 : 0, flag, N);
        gemm_layer3<<<gB, blk, 0, stream>>>(agg, x0, wt + (size_t)l * 131072,
                                            h, stats + 2 * l, N);
    }
    // final LN + relu in place, then lin2
    k_applyT<<<gElem, blk, 0, stream>>>(h, stats + 2 * (NLAYERS - 1), invTotal,
                                        gam, bet, (size_t)(NLAYERS - 1) * DH,
                                        flag, (int)NDH);
    gemm_mfma<DOUT, DH, 1><<<gB, blk, 0, stream>>>((const short*)h, w2t, lin2_b,
                                                   flag, d_out, N);
}